// Round 10
// baseline (450.653 us; speedup 1.0000x reference)
//
#include <hip/hip_runtime.h>
#include <hip/hip_bf16.h>

#define N_NODES 50000
#define E_EDGES 800000
#define EP_EDGES 850000   // E + N self loops
#define IN_DIM 160
#define HEADS 4
#define HID 64
#define C1 256            // HEADS*HID
#define NEG_SLOPE 0.2f
#define BN_EPS 1e-5f

typedef __attribute__((ext_vector_type(8))) short bf16x8;
typedef __attribute__((ext_vector_type(4))) float f32x4;

__device__ __forceinline__ float b2f(ushort u) {
    return __uint_as_float(((unsigned)u) << 16);
}
__device__ __forceinline__ ushort f2b(float f) {
    __hip_bfloat16 h = __float2bfloat16(f);
    return *reinterpret_cast<ushort*>(&h);
}
__device__ __forceinline__ float lo16(uint u) { return __uint_as_float(u << 16); }
__device__ __forceinline__ float hi16(uint u) { return __uint_as_float(u & 0xffff0000u); }

// ---- in-kernel dtype probes (wave-wide, 1 read + ballot) ----
// float tensors fp32? (bf16 x~N(0,1): ~64/64 samples in range; fp32 mantissa words: ~10/64)
__device__ __forceinline__ bool probe_f32(const ushort* xraw) {
    int lane = threadIdx.x & 63;
    float a = fabsf(b2f(xraw[2 * lane]));
    unsigned long long m = __ballot(a > 1e-6f && a < 1e6f);
    return __popcll(m) < 48;
}
// edge_index int64? (odd int32 words all zero)
__device__ __forceinline__ bool probe_i64(const int* eraw) {
    int lane = threadIdx.x & 63;
    unsigned long long m = __ballot(eraw[2 * lane + 1] != 0);
    return __popcll(m) < 8;
}

// DPP-based add of a permuted copy: pure VALU pipe
template<int CTRL>
__device__ __forceinline__ float dpp_add(float p) {
    int t = __builtin_amdgcn_update_dpp(0, __float_as_int(p), CTRL, 0xf, 0xf, true);
    return p + __int_as_float(t);
}
// sum over each 8-lane group; all 8 lanes get the group total
__device__ __forceinline__ float grp8_sum(float p) {
    p = dpp_add<0xB1>(p);    // quad_perm xor1
    p = dpp_add<0x4E>(p);    // quad_perm xor2
    p = dpp_add<0x141>(p);   // row_half_mirror (combines the two quads)
    return p;
}

// ---------------- canonicalize x -> bf16 (also zeroes deg) ----------------
__global__ void cvt_x_k(const void* __restrict__ src, ushort* __restrict__ dst,
                        int* __restrict__ deg) {
    const bool f32 = probe_f32((const ushort*)src);
    int i = blockIdx.x * 256 + threadIdx.x;
    if (i < N_NODES) deg[i] = 0;
    if (i >= N_NODES * IN_DIM) return;
    dst[i] = f32 ? f2b(((const float*)src)[i]) : ((const ushort*)src)[i];
}

// ---------------- merged: weight swizzle (raw->MFMA frag order) + small-param canonicalize ----------------
struct SW2 {
    const void* W[5];    // raw Wl1, Wr1, Ws, Wl2, Wr2
    ushort* D[5];
    int NT[5];
    int base[5];
    const void* sp[19];  // raw small tensors
    const void* xraw;
};

__global__ void swzp_k(SW2 s, ushort* __restrict__ params) {
    const bool f32 = probe_f32((const ushort*)s.xraw);
    if (blockIdx.x < 61) {
        int idx = blockIdx.x * 256 + threadIdx.x;   // < 15616
        int seg = 0;
        #pragma unroll
        for (int k = 1; k < 5; ++k) seg += (idx >= s.base[k]) ? 1 : 0;
        int li = idx - s.base[seg];
        int NT = s.NT[seg];
        int N = NT << 4;
        int lane = li & 63;
        int ft = li >> 6;
        int kb = ft / NT, t = ft - kb * NT;
        int q = lane >> 4, m = lane & 15;
        const float* pf = (const float*)s.W[seg];
        const ushort* pu = (const ushort*)s.W[seg];
        ushort* d = s.D[seg] + (size_t)li * 8;
        #pragma unroll
        for (int j = 0; j < 8; ++j) {
            size_t src = (size_t)(kb * 32 + q * 8 + j) * N + t * 16 + m;
            d[j] = f32 ? f2b(pf[src]) : pu[src];
        }
    } else {
        const int SZ[19] = {256,256,256,256,256,256,256,256,
                            64,64,64,64,64,64,64,64,64,64, 1};
        const int OF[19] = {40960,82176,82432,82688,82944,83200,83456,83712,
                            100352,116800,116864,116928,116992,117056,117120,117184,
                            127488,127552, 127616};
        for (int e = threadIdx.x; e < 2689; e += 256) {
            int rem = e, t = 0;
            while (rem >= SZ[t]) { rem -= SZ[t]; ++t; }
            const float* pf = (const float*)s.sp[t];
            const ushort* pu = (const ushort*)s.sp[t];
            params[OF[t] + rem] = f32 ? f2b(pf[rem]) : pu[rem];
        }
    }
}

// ---------------- CSR build (reads raw edge_index, self-probed stride) ----------------
__global__ void hist_k(const int* __restrict__ ei, int* __restrict__ deg) {
    const bool i64 = probe_i64(ei);
    int e = blockIdx.x * 256 + threadIdx.x;
    if (e >= EP_EDGES) return;
    int dst;
    if (e < E_EDGES) {
        int idx = E_EDGES + e;
        dst = i64 ? ei[2 * idx] : ei[idx];
    } else dst = e - E_EDGES;
    atomicAdd(&deg[dst], 1);
}

__global__ __launch_bounds__(1024) void scan1_k(const int* __restrict__ deg,
                                                int* __restrict__ exc,
                                                int* __restrict__ bsum) {
    __shared__ int s[1024];
    int i = blockIdx.x * 1024 + threadIdx.x;
    int v = (i < N_NODES) ? deg[i] : 0;
    s[threadIdx.x] = v;
    __syncthreads();
    for (int off = 1; off < 1024; off <<= 1) {
        int t = (threadIdx.x >= off) ? s[threadIdx.x - off] : 0;
        __syncthreads();
        s[threadIdx.x] += t;
        __syncthreads();
    }
    if (i < N_NODES) exc[i] = s[threadIdx.x] - v;
    if (threadIdx.x == 1023) bsum[blockIdx.x] = s[1023];
}

// scan3 now also folds the (tiny) scan of block sums: each block needs only
// prefix(bsum[0 .. blockIdx.x>>2)) since its 256 indices live in one 1024-chunk.
__global__ void scan3_k(int* __restrict__ row_ptr, const int* __restrict__ bsum,
                        int* __restrict__ rowcur) {
    const int chunk = blockIdx.x >> 2;     // = i >> 10 for all i in this block
    const int lane = threadIdx.x & 63;
    int v = (lane < chunk) ? bsum[lane] : 0;   // chunk <= 48 < 64
    #pragma unroll
    for (int d = 32; d > 0; d >>= 1) v += __shfl_xor(v, d);
    int i = blockIdx.x * 256 + threadIdx.x;
    if (i >= N_NODES) return;
    int rp = row_ptr[i] + v;
    row_ptr[i] = rp;
    rowcur[i] = rp;
    if (i == 0) row_ptr[N_NODES] = EP_EDGES;
}

__global__ void scatter_k(const int* __restrict__ ei,
                          int* __restrict__ rowcur, int* __restrict__ col) {
    const bool i64 = probe_i64(ei);
    int e = blockIdx.x * 256 + threadIdx.x;
    if (e >= EP_EDGES) return;
    int src, dst;
    if (e < E_EDGES) {
        if (i64) { src = ei[2 * e]; dst = ei[2 * (E_EDGES + e)]; }
        else     { src = ei[e];     dst = ei[E_EDGES + e]; }
    } else { src = e - E_EDGES; dst = src; }
    int pos = atomicAdd(&rowcur[dst], 1);
    col[pos] = src;
}

// ---------------- fused layer-1 MFMA GEMM, split-N, 2 row-tiles/wave ----------------
__global__ __launch_bounds__(256) void gemm3_k(const ushort* __restrict__ A,
                                               const ushort* __restrict__ B1,
                                               const ushort* __restrict__ B2,
                                               const ushort* __restrict__ B3,
                                               const ushort* __restrict__ bi1,
                                               const ushort* __restrict__ bi2,
                                               const ushort* __restrict__ bi3,
                                               ushort* __restrict__ o1,
                                               ushort* __restrict__ o2,
                                               ushort* __restrict__ o3,
                                               int M) {
    const int wave = threadIdx.x >> 6;
    const int lane = threadIdx.x & 63;
    const int ch = blockIdx.y;
    const int row0 = blockIdx.x * 128 + wave * 32;
    if (row0 >= M) return;
    int ar0 = row0 + (lane & 15);      if (ar0 >= M) ar0 = M - 1;
    int ar1 = row0 + 16 + (lane & 15); if (ar1 >= M) ar1 = M - 1;
    const ushort* ap0 = A + (size_t)ar0 * IN_DIM + (lane >> 4) * 8;
    const ushort* ap1 = A + (size_t)ar1 * IN_DIM + (lane >> 4) * 8;
    bf16x8 af0[5], af1[5];
    #pragma unroll
    for (int kb = 0; kb < 5; ++kb) {
        af0[kb] = *(const bf16x8*)(ap0 + kb * 32);
        af1[kb] = *(const bf16x8*)(ap1 + kb * 32);
    }
    const bf16x8* b1 = (const bf16x8*)B1;
    const bf16x8* b2 = (const bf16x8*)B2;
    const bf16x8* b3 = (const bf16x8*)B3;
    f32x4 aL[2][8] = {}, aR[2][8] = {}, aS[2][2] = {};
    #pragma unroll
    for (int kb = 0; kb < 5; ++kb) {
        #pragma unroll
        for (int j = 0; j < 8; ++j) {
            bf16x8 b = b1[(kb * 16 + ch * 8 + j) * 64 + lane];
            aL[0][j] = __builtin_amdgcn_mfma_f32_16x16x32_bf16(af0[kb], b, aL[0][j], 0, 0, 0);
            aL[1][j] = __builtin_amdgcn_mfma_f32_16x16x32_bf16(af1[kb], b, aL[1][j], 0, 0, 0);
        }
        #pragma unroll
        for (int j = 0; j < 8; ++j) {
            bf16x8 b = b2[(kb * 16 + ch * 8 + j) * 64 + lane];
            aR[0][j] = __builtin_amdgcn_mfma_f32_16x16x32_bf16(af0[kb], b, aR[0][j], 0, 0, 0);
            aR[1][j] = __builtin_amdgcn_mfma_f32_16x16x32_bf16(af1[kb], b, aR[1][j], 0, 0, 0);
        }
        #pragma unroll
        for (int j = 0; j < 2; ++j) {
            bf16x8 b = b3[(kb * 4 + ch * 2 + j) * 64 + lane];
            aS[0][j] = __builtin_amdgcn_mfma_f32_16x16x32_bf16(af0[kb], b, aS[0][j], 0, 0, 0);
            aS[1][j] = __builtin_amdgcn_mfma_f32_16x16x32_bf16(af1[kb], b, aS[1][j], 0, 0, 0);
        }
    }
    const int cn = lane & 15, cq = lane >> 4;
    #pragma unroll
    for (int rt = 0; rt < 2; ++rt) {
        #pragma unroll
        for (int j = 0; j < 8; ++j) {
            int colc = (ch * 8 + j) * 16 + cn;
            float bbL = b2f(bi1[colc]);
            float bbR = b2f(bi2[colc]);
            #pragma unroll
            for (int r = 0; r < 4; ++r) {
                int grow = row0 + rt * 16 + cq * 4 + r;
                if (grow < M) {
                    o1[(size_t)grow * C1 + colc] = f2b(aL[rt][j][r] + bbL);
                    o2[(size_t)grow * C1 + colc] = f2b(aR[rt][j][r] + bbR);
                }
            }
        }
        #pragma unroll
        for (int j = 0; j < 2; ++j) {
            int colc = (ch * 2 + j) * 16 + cn;
            float bb = b2f(bi3[colc]);
            #pragma unroll
            for (int r = 0; r < 4; ++r) {
                int grow = row0 + rt * 16 + cq * 4 + r;
                if (grow < M)
                    o3[(size_t)grow * HID + colc] = f2b(aS[rt][j][r] + bb);
            }
        }
    }
}

// ---------------- fused layer-2 MFMA GEMM: xl2(64) + xr2(64), K=256 ----------------
__global__ __launch_bounds__(256) void gemm2_k(const ushort* __restrict__ A,
                                               const ushort* __restrict__ B1,
                                               const ushort* __restrict__ B2,
                                               const ushort* __restrict__ bi1,
                                               const ushort* __restrict__ bi2,
                                               ushort* __restrict__ o1,
                                               ushort* __restrict__ o2,
                                               int M) {
    const int wave = threadIdx.x >> 6;
    const int lane = threadIdx.x & 63;
    const int row0 = blockIdx.x * 64 + wave * 16;
    if (row0 >= M) return;
    int arow = row0 + (lane & 15);
    if (arow >= M) arow = M - 1;
    const ushort* aptr = A + (size_t)arow * C1 + (lane >> 4) * 8;
    const bf16x8* b1 = (const bf16x8*)B1;
    const bf16x8* b2 = (const bf16x8*)B2;
    f32x4 aL[4] = {}, aR[4] = {};
    #pragma unroll
    for (int kb = 0; kb < 8; ++kb) {
        bf16x8 af = *(const bf16x8*)(aptr + kb * 32);
        #pragma unroll
        for (int t = 0; t < 4; ++t)
            aL[t] = __builtin_amdgcn_mfma_f32_16x16x32_bf16(af, b1[(kb * 4 + t) * 64 + lane], aL[t], 0, 0, 0);
        #pragma unroll
        for (int t = 0; t < 4; ++t)
            aR[t] = __builtin_amdgcn_mfma_f32_16x16x32_bf16(af, b2[(kb * 4 + t) * 64 + lane], aR[t], 0, 0, 0);
    }
    const int cn = lane & 15, cq = lane >> 4;
    #pragma unroll
    for (int t = 0; t < 4; ++t) {
        float bbL = b2f(bi1[t * 16 + cn]);
        float bbR = b2f(bi2[t * 16 + cn]);
        #pragma unroll
        for (int r = 0; r < 4; ++r) {
            int grow = row0 + cq * 4 + r;
            if (grow < M) {
                o1[(size_t)grow * HID + t * 16 + cn] = f2b(aL[t][r] + bbL);
                o2[(size_t)grow * HID + t * 16 + cn] = f2b(aR[t][r] + bbR);
            }
        }
    }
}

// ---------------- conv1: 8 lanes/edge, 8 ch/lane (uint4), pipelined gather ----------------
__global__ __launch_bounds__(256) void conv1_k(const ushort* __restrict__ xl,
                                               const ushort* __restrict__ xr,
                                               const int* __restrict__ row_ptr,
                                               const int* __restrict__ col,
                                               const ushort* __restrict__ att,
                                               const ushort* __restrict__ bias1,
                                               const ushort* __restrict__ g1,
                                               const ushort* __restrict__ b1,
                                               const ushort* __restrict__ m1,
                                               const ushort* __restrict__ v1,
                                               ushort* __restrict__ h1out) {
    const int n = blockIdx.x;
    const int h = threadIdx.x >> 6;          // wave = head
    const int lane = threadIdx.x & 63;
    const int slot = lane >> 3;              // edge slot 0..7
    const int c = lane & 7;                  // uint4 group within head
    const uint cpi = h * 8 + c;              // uint4 index within 32-uint4 row
    const uint4* xl4 = (const uint4*)xl;
    const uint4 xru = ((const uint4*)xr)[(size_t)n * 32 + cpi];
    const float xr0 = lo16(xru.x), xr1 = hi16(xru.x);
    const float xr2 = lo16(xru.y), xr3 = hi16(xru.y);
    const float xr4 = lo16(xru.z), xr5 = hi16(xru.z);
    const float xr6 = lo16(xru.w), xr7 = hi16(xru.w);
    const uint4 atu = ((const uint4*)att)[cpi];
    const float at0 = lo16(atu.x), at1 = hi16(atu.x);
    const float at2 = lo16(atu.y), at3 = hi16(atu.y);
    const float at4 = lo16(atu.z), at5 = hi16(atu.z);
    const float at6 = lo16(atu.w), at7 = hi16(atu.w);
    const int e0 = row_ptr[n], e1 = row_ptr[n + 1];
    float a0 = 0.f, a1 = 0.f, a2 = 0.f, a3 = 0.f;
    float a4 = 0.f, a5 = 0.f, a6 = 0.f, a7 = 0.f, den = 0.f;
    int j0 = e0 + slot;
    uint sC = (uint)col[j0 < e1 ? j0 : e1 - 1];
    uint4 xuC = xl4[(sC << 5) + cpi];
    for (int i = e0; i < e1; i += 8) {
        // prefetch next trip (gather in flight during compute)
        const int jn = i + 8 + slot;
        const uint sN = (uint)col[jn < e1 ? jn : e1 - 1];
        const uint4 xuN = xl4[(sN << 5) + cpi];
        const bool valid = (i + slot) < e1;
        const float x0 = lo16(xuC.x), x1 = hi16(xuC.x);
        const float x2 = lo16(xuC.y), x3 = hi16(xuC.y);
        const float x4 = lo16(xuC.z), x5 = hi16(xuC.z);
        const float x6 = lo16(xuC.w), x7 = hi16(xuC.w);
        float t0 = x0 + xr0; t0 = fmaxf(t0, t0 * NEG_SLOPE);
        float t1 = x1 + xr1; t1 = fmaxf(t1, t1 * NEG_SLOPE);
        float t2 = x2 + xr2; t2 = fmaxf(t2, t2 * NEG_SLOPE);
        float t3 = x3 + xr3; t3 = fmaxf(t3, t3 * NEG_SLOPE);
        float t4 = x4 + xr4; t4 = fmaxf(t4, t4 * NEG_SLOPE);
        float t5 = x5 + xr5; t5 = fmaxf(t5, t5 * NEG_SLOPE);
        float t6 = x6 + xr6; t6 = fmaxf(t6, t6 * NEG_SLOPE);
        float t7 = x7 + xr7; t7 = fmaxf(t7, t7 * NEG_SLOPE);
        float p = fmaf(t0, at0, t1 * at1);
        p = fmaf(t2, at2, p); p = fmaf(t3, at3, p);
        p = fmaf(t4, at4, p); p = fmaf(t5, at5, p);
        p = fmaf(t6, at6, p); p = fmaf(t7, at7, p);
        p = grp8_sum(p);
        const float w = valid ? __expf(fminf(p, 60.f)) : 0.f;
        a0 = fmaf(w, x0, a0); a1 = fmaf(w, x1, a1);
        a2 = fmaf(w, x2, a2); a3 = fmaf(w, x3, a3);
        a4 = fmaf(w, x4, a4); a5 = fmaf(w, x5, a5);
        a6 = fmaf(w, x6, a6); a7 = fmaf(w, x7, a7);
        den += w;
        xuC = xuN;
    }
    // reduce across the 8 edge slots (lanes differing in bits 3..5)
    #pragma unroll
    for (int d = 8; d < 64; d <<= 1) {
        a0 += __shfl_xor(a0, d); a1 += __shfl_xor(a1, d);
        a2 += __shfl_xor(a2, d); a3 += __shfl_xor(a3, d);
        a4 += __shfl_xor(a4, d); a5 += __shfl_xor(a5, d);
        a6 += __shfl_xor(a6, d); a7 += __shfl_xor(a7, d);
        den += __shfl_xor(den, d);
    }
    if (lane < 8) {
        const uint pi = h * 8 + lane;
        const float inv = 1.f / den;
        const uint4 biu = ((const uint4*)bias1)[pi];
        const uint4 gu  = ((const uint4*)g1)[pi];
        const uint4 bu  = ((const uint4*)b1)[pi];
        const uint4 mu  = ((const uint4*)m1)[pi];
        const uint4 vu  = ((const uint4*)v1)[pi];
        const float af_[8] = {a0, a1, a2, a3, a4, a5, a6, a7};
        const uint bi_[4] = {biu.x, biu.y, biu.z, biu.w};
        const uint g_[4]  = {gu.x, gu.y, gu.z, gu.w};
        const uint b_[4]  = {bu.x, bu.y, bu.z, bu.w};
        const uint m_[4]  = {mu.x, mu.y, mu.z, mu.w};
        const uint v_[4]  = {vu.x, vu.y, vu.z, vu.w};
        uint ow[4];
        #pragma unroll
        for (int k = 0; k < 4; ++k) {
            float olo = fmaf(af_[2 * k], inv, lo16(bi_[k]));
            float ohi = fmaf(af_[2 * k + 1], inv, hi16(bi_[k]));
            float slo = lo16(g_[k]) * rsqrtf(lo16(v_[k]) + BN_EPS);
            float shi = hi16(g_[k]) * rsqrtf(hi16(v_[k]) + BN_EPS);
            float hlo = fmaxf((olo - lo16(m_[k])) * slo + lo16(b_[k]), 0.f);
            float hhi = fmaxf((ohi - hi16(m_[k])) * shi + hi16(b_[k]), 0.f);
            ow[k] = (uint)f2b(hlo) | ((uint)f2b(hhi) << 16);
        }
        uint4 ou; ou.x = ow[0]; ou.y = ow[1]; ou.z = ow[2]; ou.w = ow[3];
        ((uint4*)h1out)[(size_t)n * 32 + pi] = ou;
    }
}

// ---------------- conv2 + BN2 + relu + skip + output linear ----------------
__global__ __launch_bounds__(256) void conv2_k(const ushort* __restrict__ xl,
                                               const ushort* __restrict__ xr,
                                               const ushort* __restrict__ xskip,
                                               const int* __restrict__ row_ptr,
                                               const int* __restrict__ col,
                                               const ushort* __restrict__ att2,
                                               const ushort* __restrict__ bias2,
                                               const ushort* __restrict__ g2,
                                               const ushort* __restrict__ bb2,
                                               const ushort* __restrict__ m2,
                                               const ushort* __restrict__ v2,
                                               const ushort* __restrict__ Wo,
                                               const ushort* __restrict__ bo,
                                               void* __restrict__ out,
                                               const ushort* __restrict__ xraw) {
    const bool f32out = probe_f32(xraw);
    const int n = blockIdx.x * 4 + (threadIdx.x >> 6);
    if (n >= N_NODES) return;
    const int lane = threadIdx.x & 63;
    const int slot = lane >> 3;
    const uint c = lane & 7;                 // uint4 index within 8-uint4 row
    const uint4* xl4 = (const uint4*)xl;
    const uint4 xru = ((const uint4*)xr)[(size_t)n * 8 + c];
    const float xr0 = lo16(xru.x), xr1 = hi16(xru.x);
    const float xr2 = lo16(xru.y), xr3 = hi16(xru.y);
    const float xr4 = lo16(xru.z), xr5 = hi16(xru.z);
    const float xr6 = lo16(xru.w), xr7 = hi16(xru.w);
    const uint4 atu = ((const uint4*)att2)[c];
    const float at0 = lo16(atu.x), at1 = hi16(atu.x);
    const float at2 = lo16(atu.y), at3 = hi16(atu.y);
    const float at4 = lo16(atu.z), at5 = hi16(atu.z);
    const float at6 = lo16(atu.w), at7 = hi16(atu.w);
    const int e0 = row_ptr[n], e1 = row_ptr[n + 1];
    float a0 = 0.f, a1 = 0.f, a2 = 0.f, a3 = 0.f;
    float a4 = 0.f, a5 = 0.f, a6 = 0.f, a7 = 0.f, den = 0.f;
    int j0 = e0 + slot;
    uint sC = (uint)col[j0 < e1 ? j0 : e1 - 1];
    uint4 xuC = xl4[(sC << 3) + c];
    for (int i = e0; i < e1; i += 8) {
        const int jn = i + 8 + slot;
        const uint sN = (uint)col[jn < e1 ? jn : e1 - 1];
        const uint4 xuN = xl4[(sN << 3) + c];
        const bool valid = (i + slot) < e1;
        const float x0 = lo16(xuC.x), x1 = hi16(xuC.x);
        const float x2 = lo16(xuC.y), x3 = hi16(xuC.y);
        const float x4 = lo16(xuC.z), x5 = hi16(xuC.z);
        const float x6 = lo16(xuC.w), x7 = hi16(xuC.w);
        float t0 = x0 + xr0; t0 = fmaxf(t0, t0 * NEG_SLOPE);
        float t1 = x1 + xr1; t1 = fmaxf(t1, t1 * NEG_SLOPE);
        float t2 = x2 + xr2; t2 = fmaxf(t2, t2 * NEG_SLOPE);
        float t3 = x3 + xr3; t3 = fmaxf(t3, t3 * NEG_SLOPE);
        float t4 = x4 + xr4; t4 = fmaxf(t4, t4 * NEG_SLOPE);
        float t5 = x5 + xr5; t5 = fmaxf(t5, t5 * NEG_SLOPE);
        float t6 = x6 + xr6; t6 = fmaxf(t6, t6 * NEG_SLOPE);
        float t7 = x7 + xr7; t7 = fmaxf(t7, t7 * NEG_SLOPE);
        float p = fmaf(t0, at0, t1 * at1);
        p = fmaf(t2, at2, p); p = fmaf(t3, at3, p);
        p = fmaf(t4, at4, p); p = fmaf(t5, at5, p);
        p = fmaf(t6, at6, p); p = fmaf(t7, at7, p);
        p = grp8_sum(p);
        const float w = valid ? __expf(fminf(p, 60.f)) : 0.f;
        a0 = fmaf(w, x0, a0); a1 = fmaf(w, x1, a1);
        a2 = fmaf(w, x2, a2); a3 = fmaf(w, x3, a3);
        a4 = fmaf(w, x4, a4); a5 = fmaf(w, x5, a5);
        a6 = fmaf(w, x6, a6); a7 = fmaf(w, x7, a7);
        den += w;
        xuC = xuN;
    }
    #pragma unroll
    for (int d = 8; d < 64; d <<= 1) {
        a0 += __shfl_xor(a0, d); a1 += __shfl_xor(a1, d);
        a2 += __shfl_xor(a2, d); a3 += __shfl_xor(a3, d);
        a4 += __shfl_xor(a4, d); a5 += __shfl_xor(a5, d);
        a6 += __shfl_xor(a6, d); a7 += __shfl_xor(a7, d);
        den += __shfl_xor(den, d);
    }
    if (lane < 8) {
        const float inv = 1.f / den;
        const uint4 biu = ((const uint4*)bias2)[lane];
        const uint4 gu  = ((const uint4*)g2)[lane];
        const uint4 bu  = ((const uint4*)bb2)[lane];
        const uint4 mu  = ((const uint4*)m2)[lane];
        const uint4 vu  = ((const uint4*)v2)[lane];
        const uint4 sku = ((const uint4*)xskip)[(size_t)n * 8 + lane];
        const uint4 wou = ((const uint4*)Wo)[lane];
        const float af_[8] = {a0, a1, a2, a3, a4, a5, a6, a7};
        const uint bi_[4] = {biu.x, biu.y, biu.z, biu.w};
        const uint g_[4]  = {gu.x, gu.y, gu.z, gu.w};
        const uint b_[4]  = {bu.x, bu.y, bu.z, bu.w};
        const uint m_[4]  = {mu.x, mu.y, mu.z, mu.w};
        const uint v_[4]  = {vu.x, vu.y, vu.z, vu.w};
        const uint sk_[4] = {sku.x, sku.y, sku.z, sku.w};
        const uint wo_[4] = {wou.x, wou.y, wou.z, wou.w};
        float d = 0.f;
        #pragma unroll
        for (int k = 0; k < 4; ++k) {
            float olo = fmaf(af_[2 * k], inv, lo16(bi_[k]));
            float ohi = fmaf(af_[2 * k + 1], inv, hi16(bi_[k]));
            float slo = lo16(g_[k]) * rsqrtf(lo16(v_[k]) + BN_EPS);
            float shi = hi16(g_[k]) * rsqrtf(hi16(v_[k]) + BN_EPS);
            float hlo = fmaxf((olo - lo16(m_[k])) * slo + lo16(b_[k]), 0.f) + lo16(sk_[k]);
            float hhi = fmaxf((ohi - hi16(m_[k])) * shi + hi16(b_[k]), 0.f) + hi16(sk_[k]);
            d = fmaf(hlo, lo16(wo_[k]), d);
            d = fmaf(hhi, hi16(wo_[k]), d);
        }
        d = grp8_sum(d);   // lanes 0..7 are one dpp group
        if (lane == 0) {
            float r = d + b2f(bo[0]);
            if (f32out) ((float*)out)[n] = r;
            else        ((ushort*)out)[n] = f2b(r);
        }
    }
}

extern "C" void kernel_launch(void* const* d_in, const int* in_sizes, int n_in,
                              void* d_out, int out_size, void* d_ws, size_t ws_size,
                              hipStream_t stream) {
    char* ws = (char*)d_ws;
    size_t off = 0;
    auto alloc = [&](size_t bytes) -> void* {
        void* p = ws + off;
        off += (bytes + 255) & ~(size_t)255;
        return p;
    };
    ushort* params  = (ushort*)alloc((size_t)127617 * 2);
    ushort* x_c     = (ushort*)alloc((size_t)N_NODES * IN_DIM * 2);
    int*    row_ptr = (int*)alloc((size_t)(N_NODES + 1) * 4);
    int*    rowcur  = (int*)alloc((size_t)N_NODES * 4);
    int*    deg     = (int*)alloc((size_t)N_NODES * 4);
    int*    colbuf  = (int*)alloc((size_t)EP_EDGES * 4);
    int*    bsum    = (int*)alloc(64 * 4);
    ushort* xl1     = (ushort*)alloc((size_t)N_NODES * C1 * 2);
    ushort* xr1     = (ushort*)alloc((size_t)N_NODES * C1 * 2);
    ushort* xskip   = (ushort*)alloc((size_t)N_NODES * HID * 2);
    ushort* h1      = (ushort*)alloc((size_t)N_NODES * C1 * 2);
    ushort* xl2     = (ushort*)alloc((size_t)N_NODES * HID * 2);
    ushort* xr2     = (ushort*)alloc((size_t)N_NODES * HID * 2);
    ushort* swzWl1  = (ushort*)alloc((size_t)IN_DIM * C1 * 2);
    ushort* swzWr1  = (ushort*)alloc((size_t)IN_DIM * C1 * 2);
    ushort* swzWs   = (ushort*)alloc((size_t)IN_DIM * HID * 2);
    ushort* swzWl2  = (ushort*)alloc((size_t)C1 * HID * 2);
    ushort* swzWr2  = (ushort*)alloc((size_t)C1 * HID * 2);

    ushort* bl1c   = params + 40960;
    ushort* br1c   = params + 82176;
    ushort* att1c  = params + 82432;
    ushort* bias1c = params + 82688;
    ushort* g1c    = params + 82944;
    ushort* b1c    = params + 83200;
    ushort* m1c    = params + 83456;
    ushort* v1c    = params + 83712;
    ushort* bl2c   = params + 100352;
    ushort* br2c   = params + 116800;
    ushort* att2c  = params + 116864;
    ushort* bias2c = params + 116928;
    ushort* g2c    = params + 116992;
    ushort* b2c    = params + 117056;
    ushort* m2c    = params + 117120;
    ushort* v2c    = params + 117184;
    ushort* bsc    = params + 127488;
    ushort* Woc    = params + 127552;
    ushort* boc    = params + 127616;

    // ---- canonicalize x (self-detecting), swizzle weights + small params ----
    cvt_x_k<<<(N_NODES * IN_DIM + 255) / 256, 256, 0, stream>>>(d_in[0], x_c, deg);

    SW2 sw;
    sw.W[0] = d_in[2];  sw.D[0] = swzWl1; sw.NT[0] = 16; sw.base[0] = 0;      // Wl1
    sw.W[1] = d_in[4];  sw.D[1] = swzWr1; sw.NT[1] = 16; sw.base[1] = 5120;   // Wr1
    sw.W[2] = d_in[22]; sw.D[2] = swzWs;  sw.NT[2] = 4;  sw.base[2] = 10240;  // Ws
    sw.W[3] = d_in[12]; sw.D[3] = swzWl2; sw.NT[3] = 4;  sw.base[3] = 11520;  // Wl2
    sw.W[4] = d_in[14]; sw.D[4] = swzWr2; sw.NT[4] = 4;  sw.base[4] = 13568;  // Wr2
    const int spidx[19] = {3,5,6,7,8,9,10,11, 13,15,16,17,18,19,20,21, 23,24, 25};
    for (int i = 0; i < 19; ++i) sw.sp[i] = d_in[spidx[i]];
    sw.xraw = d_in[0];
    swzp_k<<<62, 256, 0, stream>>>(sw, params);

    const int NB_N = (N_NODES + 255) / 256;        // 196
    const int NB_E = (EP_EDGES + 255) / 256;       // 3321
    const int NB_S = (N_NODES + 1023) / 1024;      // 49

    // ---- CSR build (reads raw edge_index, self-probing) ----
    const int* ei_raw = (const int*)d_in[1];
    hist_k<<<NB_E, 256, 0, stream>>>(ei_raw, deg);
    scan1_k<<<NB_S, 1024, 0, stream>>>(deg, row_ptr, bsum);
    scan3_k<<<NB_N, 256, 0, stream>>>(row_ptr, bsum, rowcur);
    scatter_k<<<NB_E, 256, 0, stream>>>(ei_raw, rowcur, colbuf);

    // ---- layer-1 linear transforms (+ skip), fused MFMA (split-N, 2 row-tiles/wave) ----
    gemm3_k<<<dim3((N_NODES + 127) / 128, 2), 256, 0, stream>>>(
        x_c, swzWl1, swzWr1, swzWs, bl1c, br1c, bsc, xl1, xr1, xskip, N_NODES);

    // ---- conv1 edge aggregation + BN1 + relu ----
    conv1_k<<<N_NODES, 256, 0, stream>>>(xl1, xr1, row_ptr, colbuf, att1c, bias1c,
                                         g1c, b1c, m1c, v1c, h1);

    // ---- layer-2 linear transforms, fused MFMA ----
    gemm2_k<<<(N_NODES + 63) / 64, 256, 0, stream>>>(h1, swzWl2, swzWr2, bl2c, br2c,
                                                     xl2, xr2, N_NODES);

    // ---- conv2 + BN2 + relu + skip + output linear ----
    conv2_k<<<(N_NODES + 3) / 4, 256, 0, stream>>>(xl2, xr2, xskip, row_ptr, colbuf,
                                                   att2c, bias2c, g2c, b2c, m2c, v2c,
                                                   Woc, boc, d_out, (const ushort*)d_in[0]);
}

// Round 11
// 424.810 us; speedup vs baseline: 1.0608x; 1.0608x over previous
//
#include <hip/hip_runtime.h>
#include <hip/hip_bf16.h>

#define N_NODES 50000
#define E_EDGES 800000
#define EP_EDGES 850000   // E + N self loops
#define IN_DIM 160
#define HEADS 4
#define HID 64
#define C1 256            // HEADS*HID
#define NEG_SLOPE 0.2f
#define BN_EPS 1e-5f

typedef __attribute__((ext_vector_type(8))) short bf16x8;
typedef __attribute__((ext_vector_type(4))) float f32x4;

__device__ __forceinline__ float b2f(ushort u) {
    return __uint_as_float(((unsigned)u) << 16);
}
__device__ __forceinline__ ushort f2b(float f) {
    __hip_bfloat16 h = __float2bfloat16(f);
    return *reinterpret_cast<ushort*>(&h);
}
__device__ __forceinline__ float lo16(uint u) { return __uint_as_float(u << 16); }
__device__ __forceinline__ float hi16(uint u) { return __uint_as_float(u & 0xffff0000u); }

// ---- in-kernel dtype probes (wave-wide, 1 read + ballot) ----
__device__ __forceinline__ bool probe_f32(const ushort* xraw) {
    int lane = threadIdx.x & 63;
    float a = fabsf(b2f(xraw[2 * lane]));
    unsigned long long m = __ballot(a > 1e-6f && a < 1e6f);
    return __popcll(m) < 48;
}
__device__ __forceinline__ bool probe_i64(const int* eraw) {
    int lane = threadIdx.x & 63;
    unsigned long long m = __ballot(eraw[2 * lane + 1] != 0);
    return __popcll(m) < 8;
}

// DPP-based add of a permuted copy: pure VALU pipe
template<int CTRL>
__device__ __forceinline__ float dpp_add(float p) {
    int t = __builtin_amdgcn_update_dpp(0, __float_as_int(p), CTRL, 0xf, 0xf, true);
    return p + __int_as_float(t);
}
// sum over each 16-lane row; all 16 lanes get the row total
__device__ __forceinline__ float row16_sum(float p) {
    p = dpp_add<0xB1>(p);    // quad_perm xor1
    p = dpp_add<0x4E>(p);    // quad_perm xor2
    p = dpp_add<0x124>(p);   // row_ror:4
    p = dpp_add<0x128>(p);   // row_ror:8
    return p;
}

// ---------------- canonicalize x -> bf16 (also zeroes deg) ----------------
__global__ void cvt_x_k(const void* __restrict__ src, ushort* __restrict__ dst,
                        int* __restrict__ deg) {
    const bool f32 = probe_f32((const ushort*)src);
    int i = blockIdx.x * 256 + threadIdx.x;
    if (i < N_NODES) deg[i] = 0;
    if (i >= N_NODES * IN_DIM) return;
    dst[i] = f32 ? f2b(((const float*)src)[i]) : ((const ushort*)src)[i];
}

// ---------------- merged: weight swizzle + small-param canonicalize ----------------
struct SW2 {
    const void* W[5];    // raw Wl1, Wr1, Ws, Wl2, Wr2
    ushort* D[5];
    int NT[5];
    int base[5];
    const void* sp[19];  // raw small tensors
    const void* xraw;
};

__global__ void swzp_k(SW2 s, ushort* __restrict__ params) {
    const bool f32 = probe_f32((const ushort*)s.xraw);
    if (blockIdx.x < 61) {
        int idx = blockIdx.x * 256 + threadIdx.x;   // < 15616
        int seg = 0;
        #pragma unroll
        for (int k = 1; k < 5; ++k) seg += (idx >= s.base[k]) ? 1 : 0;
        int li = idx - s.base[seg];
        int NT = s.NT[seg];
        int N = NT << 4;
        int lane = li & 63;
        int ft = li >> 6;
        int kb = ft / NT, t = ft - kb * NT;
        int q = lane >> 4, m = lane & 15;
        const float* pf = (const float*)s.W[seg];
        const ushort* pu = (const ushort*)s.W[seg];
        ushort* d = s.D[seg] + (size_t)li * 8;
        #pragma unroll
        for (int j = 0; j < 8; ++j) {
            size_t src = (size_t)(kb * 32 + q * 8 + j) * N + t * 16 + m;
            d[j] = f32 ? f2b(pf[src]) : pu[src];
        }
    } else {
        const int SZ[19] = {256,256,256,256,256,256,256,256,
                            64,64,64,64,64,64,64,64,64,64, 1};
        const int OF[19] = {40960,82176,82432,82688,82944,83200,83456,83712,
                            100352,116800,116864,116928,116992,117056,117120,117184,
                            127488,127552, 127616};
        for (int e = threadIdx.x; e < 2689; e += 256) {
            int rem = e, t = 0;
            while (rem >= SZ[t]) { rem -= SZ[t]; ++t; }
            const float* pf = (const float*)s.sp[t];
            const ushort* pu = (const ushort*)s.sp[t];
            params[OF[t] + rem] = f32 ? f2b(pf[rem]) : pu[rem];
        }
    }
}

// ---------------- CSR build (reads raw edge_index, self-probed stride) ----------------
__global__ void hist_k(const int* __restrict__ ei, int* __restrict__ deg) {
    const bool i64 = probe_i64(ei);
    int e = blockIdx.x * 256 + threadIdx.x;
    if (e >= EP_EDGES) return;
    int dst;
    if (e < E_EDGES) {
        int idx = E_EDGES + e;
        dst = i64 ? ei[2 * idx] : ei[idx];
    } else dst = e - E_EDGES;
    atomicAdd(&deg[dst], 1);
}

__global__ __launch_bounds__(1024) void scan1_k(const int* __restrict__ deg,
                                                int* __restrict__ exc,
                                                int* __restrict__ bsum) {
    __shared__ int s[1024];
    int i = blockIdx.x * 1024 + threadIdx.x;
    int v = (i < N_NODES) ? deg[i] : 0;
    s[threadIdx.x] = v;
    __syncthreads();
    for (int off = 1; off < 1024; off <<= 1) {
        int t = (threadIdx.x >= off) ? s[threadIdx.x - off] : 0;
        __syncthreads();
        s[threadIdx.x] += t;
        __syncthreads();
    }
    if (i < N_NODES) exc[i] = s[threadIdx.x] - v;
    if (threadIdx.x == 1023) bsum[blockIdx.x] = s[1023];
}

// scan3 folds the tiny scan of block sums (each block needs prefix(bsum[0..blockIdx.x>>2)))
__global__ void scan3_k(int* __restrict__ row_ptr, const int* __restrict__ bsum,
                        int* __restrict__ rowcur) {
    const int chunk = blockIdx.x >> 2;
    const int lane = threadIdx.x & 63;
    int v = (lane < chunk) ? bsum[lane] : 0;   // chunk <= 48 < 64
    #pragma unroll
    for (int d = 32; d > 0; d >>= 1) v += __shfl_xor(v, d);
    int i = blockIdx.x * 256 + threadIdx.x;
    if (i >= N_NODES) return;
    int rp = row_ptr[i] + v;
    row_ptr[i] = rp;
    rowcur[i] = rp;
    if (i == 0) row_ptr[N_NODES] = EP_EDGES;
}

__global__ void scatter_k(const int* __restrict__ ei,
                          int* __restrict__ rowcur, int* __restrict__ col) {
    const bool i64 = probe_i64(ei);
    int e = blockIdx.x * 256 + threadIdx.x;
    if (e >= EP_EDGES) return;
    int src, dst;
    if (e < E_EDGES) {
        if (i64) { src = ei[2 * e]; dst = ei[2 * (E_EDGES + e)]; }
        else     { src = ei[e];     dst = ei[E_EDGES + e]; }
    } else { src = e - E_EDGES; dst = src; }
    int pos = atomicAdd(&rowcur[dst], 1);
    col[pos] = src;
}

// ---------------- fused layer-1 MFMA GEMM, split-N, 2 row-tiles/wave ----------------
__global__ __launch_bounds__(256) void gemm3_k(const ushort* __restrict__ A,
                                               const ushort* __restrict__ B1,
                                               const ushort* __restrict__ B2,
                                               const ushort* __restrict__ B3,
                                               const ushort* __restrict__ bi1,
                                               const ushort* __restrict__ bi2,
                                               const ushort* __restrict__ bi3,
                                               ushort* __restrict__ o1,
                                               ushort* __restrict__ o2,
                                               ushort* __restrict__ o3,
                                               int M) {
    const int wave = threadIdx.x >> 6;
    const int lane = threadIdx.x & 63;
    const int ch = blockIdx.y;
    const int row0 = blockIdx.x * 128 + wave * 32;
    if (row0 >= M) return;
    int ar0 = row0 + (lane & 15);      if (ar0 >= M) ar0 = M - 1;
    int ar1 = row0 + 16 + (lane & 15); if (ar1 >= M) ar1 = M - 1;
    const ushort* ap0 = A + (size_t)ar0 * IN_DIM + (lane >> 4) * 8;
    const ushort* ap1 = A + (size_t)ar1 * IN_DIM + (lane >> 4) * 8;
    bf16x8 af0[5], af1[5];
    #pragma unroll
    for (int kb = 0; kb < 5; ++kb) {
        af0[kb] = *(const bf16x8*)(ap0 + kb * 32);
        af1[kb] = *(const bf16x8*)(ap1 + kb * 32);
    }
    const bf16x8* b1 = (const bf16x8*)B1;
    const bf16x8* b2 = (const bf16x8*)B2;
    const bf16x8* b3 = (const bf16x8*)B3;
    f32x4 aL[2][8] = {}, aR[2][8] = {}, aS[2][2] = {};
    #pragma unroll
    for (int kb = 0; kb < 5; ++kb) {
        #pragma unroll
        for (int j = 0; j < 8; ++j) {
            bf16x8 b = b1[(kb * 16 + ch * 8 + j) * 64 + lane];
            aL[0][j] = __builtin_amdgcn_mfma_f32_16x16x32_bf16(af0[kb], b, aL[0][j], 0, 0, 0);
            aL[1][j] = __builtin_amdgcn_mfma_f32_16x16x32_bf16(af1[kb], b, aL[1][j], 0, 0, 0);
        }
        #pragma unroll
        for (int j = 0; j < 8; ++j) {
            bf16x8 b = b2[(kb * 16 + ch * 8 + j) * 64 + lane];
            aR[0][j] = __builtin_amdgcn_mfma_f32_16x16x32_bf16(af0[kb], b, aR[0][j], 0, 0, 0);
            aR[1][j] = __builtin_amdgcn_mfma_f32_16x16x32_bf16(af1[kb], b, aR[1][j], 0, 0, 0);
        }
        #pragma unroll
        for (int j = 0; j < 2; ++j) {
            bf16x8 b = b3[(kb * 4 + ch * 2 + j) * 64 + lane];
            aS[0][j] = __builtin_amdgcn_mfma_f32_16x16x32_bf16(af0[kb], b, aS[0][j], 0, 0, 0);
            aS[1][j] = __builtin_amdgcn_mfma_f32_16x16x32_bf16(af1[kb], b, aS[1][j], 0, 0, 0);
        }
    }
    const int cn = lane & 15, cq = lane >> 4;
    #pragma unroll
    for (int rt = 0; rt < 2; ++rt) {
        #pragma unroll
        for (int j = 0; j < 8; ++j) {
            int colc = (ch * 8 + j) * 16 + cn;
            float bbL = b2f(bi1[colc]);
            float bbR = b2f(bi2[colc]);
            #pragma unroll
            for (int r = 0; r < 4; ++r) {
                int grow = row0 + rt * 16 + cq * 4 + r;
                if (grow < M) {
                    o1[(size_t)grow * C1 + colc] = f2b(aL[rt][j][r] + bbL);
                    o2[(size_t)grow * C1 + colc] = f2b(aR[rt][j][r] + bbR);
                }
            }
        }
        #pragma unroll
        for (int j = 0; j < 2; ++j) {
            int colc = (ch * 2 + j) * 16 + cn;
            float bb = b2f(bi3[colc]);
            #pragma unroll
            for (int r = 0; r < 4; ++r) {
                int grow = row0 + rt * 16 + cq * 4 + r;
                if (grow < M)
                    o3[(size_t)grow * HID + colc] = f2b(aS[rt][j][r] + bb);
            }
        }
    }
}

// ---------------- fused layer-2 MFMA GEMM: xl2 + xr2, K=256, 2 row-tiles/wave ----------------
__global__ __launch_bounds__(256) void gemm2_k(const ushort* __restrict__ A,
                                               const ushort* __restrict__ B1,
                                               const ushort* __restrict__ B2,
                                               const ushort* __restrict__ bi1,
                                               const ushort* __restrict__ bi2,
                                               ushort* __restrict__ o1,
                                               ushort* __restrict__ o2,
                                               int M) {
    const int wave = threadIdx.x >> 6;
    const int lane = threadIdx.x & 63;
    const int row0 = blockIdx.x * 128 + wave * 32;
    if (row0 >= M) return;
    int ar0 = row0 + (lane & 15);      if (ar0 >= M) ar0 = M - 1;
    int ar1 = row0 + 16 + (lane & 15); if (ar1 >= M) ar1 = M - 1;
    const ushort* ap0 = A + (size_t)ar0 * C1 + (lane >> 4) * 8;
    const ushort* ap1 = A + (size_t)ar1 * C1 + (lane >> 4) * 8;
    const bf16x8* b1 = (const bf16x8*)B1;
    const bf16x8* b2 = (const bf16x8*)B2;
    f32x4 aL[2][4] = {}, aR[2][4] = {};
    #pragma unroll
    for (int kb = 0; kb < 8; ++kb) {
        bf16x8 af0 = *(const bf16x8*)(ap0 + kb * 32);
        bf16x8 af1 = *(const bf16x8*)(ap1 + kb * 32);
        #pragma unroll
        for (int t = 0; t < 4; ++t) {
            bf16x8 b = b1[(kb * 4 + t) * 64 + lane];
            aL[0][t] = __builtin_amdgcn_mfma_f32_16x16x32_bf16(af0, b, aL[0][t], 0, 0, 0);
            aL[1][t] = __builtin_amdgcn_mfma_f32_16x16x32_bf16(af1, b, aL[1][t], 0, 0, 0);
        }
        #pragma unroll
        for (int t = 0; t < 4; ++t) {
            bf16x8 b = b2[(kb * 4 + t) * 64 + lane];
            aR[0][t] = __builtin_amdgcn_mfma_f32_16x16x32_bf16(af0, b, aR[0][t], 0, 0, 0);
            aR[1][t] = __builtin_amdgcn_mfma_f32_16x16x32_bf16(af1, b, aR[1][t], 0, 0, 0);
        }
    }
    const int cn = lane & 15, cq = lane >> 4;
    #pragma unroll
    for (int rt = 0; rt < 2; ++rt) {
        #pragma unroll
        for (int t = 0; t < 4; ++t) {
            float bbL = b2f(bi1[t * 16 + cn]);
            float bbR = b2f(bi2[t * 16 + cn]);
            #pragma unroll
            for (int r = 0; r < 4; ++r) {
                int grow = row0 + rt * 16 + cq * 4 + r;
                if (grow < M) {
                    o1[(size_t)grow * HID + t * 16 + cn] = f2b(aL[rt][t][r] + bbL);
                    o2[(size_t)grow * HID + t * 16 + cn] = f2b(aR[rt][t][r] + bbR);
                }
            }
        }
    }
}

// ---------------- conv1: 4 gather chains, maskless full trips + guarded epilogue ----------------
__global__ __launch_bounds__(256) void conv1_k(const ushort* __restrict__ xl,
                                               const ushort* __restrict__ xr,
                                               const int* __restrict__ row_ptr,
                                               const int* __restrict__ col,
                                               const ushort* __restrict__ att,
                                               const ushort* __restrict__ bias1,
                                               const ushort* __restrict__ g1,
                                               const ushort* __restrict__ b1,
                                               const ushort* __restrict__ m1,
                                               const ushort* __restrict__ v1,
                                               ushort* __restrict__ h1out) {
    const int n = blockIdx.x;
    const int h = threadIdx.x >> 6;          // wave = head
    const int lane = threadIdx.x & 63;
    const int grp = lane >> 4;               // edge slot 0..3
    const int m = lane & 15;                 // channel quad
    const uint cpi = h * 16 + m;             // uint2 index within 64-uint2 row
    const uint2* xl2v = (const uint2*)xl;
    const uint2 xru = ((const uint2*)xr)[(size_t)n * 64 + cpi];
    const float xr0 = lo16(xru.x), xr1 = hi16(xru.x);
    const float xr2 = lo16(xru.y), xr3 = hi16(xru.y);
    const uint2 atu = ((const uint2*)att)[cpi];
    const float at0 = lo16(atu.x), at1 = hi16(atu.x);
    const float at2 = lo16(atu.y), at3 = hi16(atu.y);
    const int e0 = row_ptr[n], e1 = row_ptr[n + 1];
    const int deg = e1 - e0;
    const int iend = e0 + (deg & ~15);       // end of maskless full trips
    float a0 = 0.f, a1 = 0.f, a2 = 0.f, a3 = 0.f, den = 0.f;

    auto edge4 = [&](const uint2 xu, bool masked, int jbase) {
        const float x0 = lo16(xu.x), x1 = hi16(xu.x);
        const float x2 = lo16(xu.y), x3 = hi16(xu.y);
        float t0 = x0 + xr0; t0 = fmaxf(t0, t0 * NEG_SLOPE);
        float t1 = x1 + xr1; t1 = fmaxf(t1, t1 * NEG_SLOPE);
        float t2 = x2 + xr2; t2 = fmaxf(t2, t2 * NEG_SLOPE);
        float t3 = x3 + xr3; t3 = fmaxf(t3, t3 * NEG_SLOPE);
        float p = fmaf(t0, at0, fmaf(t1, at1, fmaf(t2, at2, t3 * at3)));
        p = row16_sum(p);
        float w = __expf(fminf(p, 60.f));
        if (masked) w = ((jbase + grp) < e1) ? w : 0.f;
        a0 = fmaf(w, x0, a0); a1 = fmaf(w, x1, a1);
        a2 = fmaf(w, x2, a2); a3 = fmaf(w, x3, a3);
        den += w;
    };

    uint s0_, s1_, s2_, s3_;
    {
        const int j0 = e0 + grp, j1 = j0 + 4, j2 = j0 + 8, j3 = j0 + 12;
        s0_ = (uint)col[j0 < e1 ? j0 : e1 - 1];
        s1_ = (uint)col[j1 < e1 ? j1 : e1 - 1];
        s2_ = (uint)col[j2 < e1 ? j2 : e1 - 1];
        s3_ = (uint)col[j3 < e1 ? j3 : e1 - 1];
    }
    for (int i = e0; i < iend; i += 16) {
        const uint2 xu0 = xl2v[(s0_ << 6) + cpi];
        const uint2 xu1 = xl2v[(s1_ << 6) + cpi];
        const uint2 xu2 = xl2v[(s2_ << 6) + cpi];
        const uint2 xu3 = xl2v[(s3_ << 6) + cpi];
        const int j0 = i + 16 + grp, j1 = j0 + 4, j2 = j0 + 8, j3 = j0 + 12;
        s0_ = (uint)col[j0 < e1 ? j0 : e1 - 1];
        s1_ = (uint)col[j1 < e1 ? j1 : e1 - 1];
        s2_ = (uint)col[j2 < e1 ? j2 : e1 - 1];
        s3_ = (uint)col[j3 < e1 ? j3 : e1 - 1];
        edge4(xu0, false, 0);
        edge4(xu1, false, 0);
        edge4(xu2, false, 0);
        edge4(xu3, false, 0);
    }
    const int rem = e1 - iend;               // 0..15
    if (rem > 0) {
        const uint2 xu0 = xl2v[(s0_ << 6) + cpi];   // all 4 issued: MLP preserved
        const uint2 xu1 = xl2v[(s1_ << 6) + cpi];
        const uint2 xu2 = xl2v[(s2_ << 6) + cpi];
        const uint2 xu3 = xl2v[(s3_ << 6) + cpi];
        edge4(xu0, true, iend);
        if (rem > 4)  edge4(xu1, true, iend + 4);
        if (rem > 8)  edge4(xu2, true, iend + 8);
        if (rem > 12) edge4(xu3, true, iend + 12);
    }
    a0 += __shfl_xor(a0, 16); a0 += __shfl_xor(a0, 32);
    a1 += __shfl_xor(a1, 16); a1 += __shfl_xor(a1, 32);
    a2 += __shfl_xor(a2, 16); a2 += __shfl_xor(a2, 32);
    a3 += __shfl_xor(a3, 16); a3 += __shfl_xor(a3, 32);
    den += __shfl_xor(den, 16); den += __shfl_xor(den, 32);
    if (lane < 16) {
        const float inv = 1.f / den;
        const uint2 biu = ((const uint2*)bias1)[cpi];
        const uint2 gu  = ((const uint2*)g1)[cpi];
        const uint2 bu  = ((const uint2*)b1)[cpi];
        const uint2 mu  = ((const uint2*)m1)[cpi];
        const uint2 vu  = ((const uint2*)v1)[cpi];
        float o0 = fmaf(a0, inv, lo16(biu.x));
        float o1 = fmaf(a1, inv, hi16(biu.x));
        float o2 = fmaf(a2, inv, lo16(biu.y));
        float o3 = fmaf(a3, inv, hi16(biu.y));
        float s0 = lo16(gu.x) * rsqrtf(lo16(vu.x) + BN_EPS);
        float s1 = hi16(gu.x) * rsqrtf(hi16(vu.x) + BN_EPS);
        float s2 = lo16(gu.y) * rsqrtf(lo16(vu.y) + BN_EPS);
        float s3 = hi16(gu.y) * rsqrtf(hi16(vu.y) + BN_EPS);
        float h0 = fmaxf((o0 - lo16(mu.x)) * s0 + lo16(bu.x), 0.f);
        float h1v = fmaxf((o1 - hi16(mu.x)) * s1 + hi16(bu.x), 0.f);
        float h2 = fmaxf((o2 - lo16(mu.y)) * s2 + lo16(bu.y), 0.f);
        float h3 = fmaxf((o3 - hi16(mu.y)) * s3 + hi16(bu.y), 0.f);
        uint2 ou;
        ou.x = (uint)f2b(h0) | ((uint)f2b(h1v) << 16);
        ou.y = (uint)f2b(h2) | ((uint)f2b(h3) << 16);
        ((uint2*)h1out)[(size_t)n * 64 + cpi] = ou;
    }
}

// ---------------- conv2 + BN2 + relu + skip + output linear ----------------
__global__ __launch_bounds__(256) void conv2_k(const ushort* __restrict__ xl,
                                               const ushort* __restrict__ xr,
                                               const ushort* __restrict__ xskip,
                                               const int* __restrict__ row_ptr,
                                               const int* __restrict__ col,
                                               const ushort* __restrict__ att2,
                                               const ushort* __restrict__ bias2,
                                               const ushort* __restrict__ g2,
                                               const ushort* __restrict__ bb2,
                                               const ushort* __restrict__ m2,
                                               const ushort* __restrict__ v2,
                                               const ushort* __restrict__ Wo,
                                               const ushort* __restrict__ bo,
                                               void* __restrict__ out,
                                               const ushort* __restrict__ xraw) {
    const bool f32out = probe_f32(xraw);
    const int n = blockIdx.x * 4 + (threadIdx.x >> 6);
    if (n >= N_NODES) return;
    const int lane = threadIdx.x & 63;
    const int grp = lane >> 4;
    const uint m = lane & 15;                // uint2 index within 16-uint2 row
    const uint2* xl2v = (const uint2*)xl;
    const uint2 xru = ((const uint2*)xr)[(size_t)n * 16 + m];
    const float xr0 = lo16(xru.x), xr1 = hi16(xru.x);
    const float xr2 = lo16(xru.y), xr3 = hi16(xru.y);
    const uint2 atu = ((const uint2*)att2)[m];
    const float at0 = lo16(atu.x), at1 = hi16(atu.x);
    const float at2 = lo16(atu.y), at3 = hi16(atu.y);
    const int e0 = row_ptr[n], e1 = row_ptr[n + 1];
    const int deg = e1 - e0;
    const int iend = e0 + (deg & ~15);
    float a0 = 0.f, a1 = 0.f, a2 = 0.f, a3 = 0.f, den = 0.f;

    auto edge4 = [&](const uint2 xu, bool masked, int jbase) {
        const float x0 = lo16(xu.x), x1 = hi16(xu.x);
        const float x2 = lo16(xu.y), x3 = hi16(xu.y);
        float t0 = x0 + xr0; t0 = fmaxf(t0, t0 * NEG_SLOPE);
        float t1 = x1 + xr1; t1 = fmaxf(t1, t1 * NEG_SLOPE);
        float t2 = x2 + xr2; t2 = fmaxf(t2, t2 * NEG_SLOPE);
        float t3 = x3 + xr3; t3 = fmaxf(t3, t3 * NEG_SLOPE);
        float p = fmaf(t0, at0, fmaf(t1, at1, fmaf(t2, at2, t3 * at3)));
        p = row16_sum(p);
        float w = __expf(fminf(p, 60.f));
        if (masked) w = ((jbase + grp) < e1) ? w : 0.f;
        a0 = fmaf(w, x0, a0); a1 = fmaf(w, x1, a1);
        a2 = fmaf(w, x2, a2); a3 = fmaf(w, x3, a3);
        den += w;
    };

    uint s0_, s1_, s2_, s3_;
    {
        const int j0 = e0 + grp, j1 = j0 + 4, j2 = j0 + 8, j3 = j0 + 12;
        s0_ = (uint)col[j0 < e1 ? j0 : e1 - 1];
        s1_ = (uint)col[j1 < e1 ? j1 : e1 - 1];
        s2_ = (uint)col[j2 < e1 ? j2 : e1 - 1];
        s3_ = (uint)col[j3 < e1 ? j3 : e1 - 1];
    }
    for (int i = e0; i < iend; i += 16) {
        const uint2 xu0 = xl2v[(s0_ << 4) + m];
        const uint2 xu1 = xl2v[(s1_ << 4) + m];
        const uint2 xu2 = xl2v[(s2_ << 4) + m];
        const uint2 xu3 = xl2v[(s3_ << 4) + m];
        const int j0 = i + 16 + grp, j1 = j0 + 4, j2 = j0 + 8, j3 = j0 + 12;
        s0_ = (uint)col[j0 < e1 ? j0 : e1 - 1];
        s1_ = (uint)col[j1 < e1 ? j1 : e1 - 1];
        s2_ = (uint)col[j2 < e1 ? j2 : e1 - 1];
        s3_ = (uint)col[j3 < e1 ? j3 : e1 - 1];
        edge4(xu0, false, 0);
        edge4(xu1, false, 0);
        edge4(xu2, false, 0);
        edge4(xu3, false, 0);
    }
    const int rem = e1 - iend;
    if (rem > 0) {
        const uint2 xu0 = xl2v[(s0_ << 4) + m];
        const uint2 xu1 = xl2v[(s1_ << 4) + m];
        const uint2 xu2 = xl2v[(s2_ << 4) + m];
        const uint2 xu3 = xl2v[(s3_ << 4) + m];
        edge4(xu0, true, iend);
        if (rem > 4)  edge4(xu1, true, iend + 4);
        if (rem > 8)  edge4(xu2, true, iend + 8);
        if (rem > 12) edge4(xu3, true, iend + 12);
    }
    a0 += __shfl_xor(a0, 16); a0 += __shfl_xor(a0, 32);
    a1 += __shfl_xor(a1, 16); a1 += __shfl_xor(a1, 32);
    a2 += __shfl_xor(a2, 16); a2 += __shfl_xor(a2, 32);
    a3 += __shfl_xor(a3, 16); a3 += __shfl_xor(a3, 32);
    den += __shfl_xor(den, 16); den += __shfl_xor(den, 32);
    if (lane < 16) {
        const float inv = 1.f / den;
        const uint2 biu = ((const uint2*)bias2)[m];
        const uint2 gu  = ((const uint2*)g2)[m];
        const uint2 bu  = ((const uint2*)bb2)[m];
        const uint2 mu  = ((const uint2*)m2)[m];
        const uint2 vu  = ((const uint2*)v2)[m];
        const uint2 sku = ((const uint2*)xskip)[(size_t)n * 16 + m];
        const uint2 wou = ((const uint2*)Wo)[m];
        float o0 = fmaf(a0, inv, lo16(biu.x));
        float o1 = fmaf(a1, inv, hi16(biu.x));
        float o2 = fmaf(a2, inv, lo16(biu.y));
        float o3 = fmaf(a3, inv, hi16(biu.y));
        float s0 = lo16(gu.x) * rsqrtf(lo16(vu.x) + BN_EPS);
        float s1 = hi16(gu.x) * rsqrtf(hi16(vu.x) + BN_EPS);
        float s2 = lo16(gu.y) * rsqrtf(lo16(vu.y) + BN_EPS);
        float s3 = hi16(gu.y) * rsqrtf(hi16(vu.y) + BN_EPS);
        float h0 = fmaxf((o0 - lo16(mu.x)) * s0 + lo16(bu.x), 0.f) + lo16(sku.x);
        float h1v = fmaxf((o1 - hi16(mu.x)) * s1 + hi16(bu.x), 0.f) + hi16(sku.x);
        float h2 = fmaxf((o2 - lo16(mu.y)) * s2 + lo16(bu.y), 0.f) + lo16(sku.y);
        float h3 = fmaxf((o3 - hi16(mu.y)) * s3 + hi16(bu.y), 0.f) + hi16(sku.y);
        float d = fmaf(h0, lo16(wou.x), fmaf(h1v, hi16(wou.x),
                  fmaf(h2, lo16(wou.y), h3 * hi16(wou.y))));
        d = row16_sum(d);
        if (m == 0) {
            float r = d + b2f(bo[0]);
            if (f32out) ((float*)out)[n] = r;
            else        ((ushort*)out)[n] = f2b(r);
        }
    }
}

extern "C" void kernel_launch(void* const* d_in, const int* in_sizes, int n_in,
                              void* d_out, int out_size, void* d_ws, size_t ws_size,
                              hipStream_t stream) {
    char* ws = (char*)d_ws;
    size_t off = 0;
    auto alloc = [&](size_t bytes) -> void* {
        void* p = ws + off;
        off += (bytes + 255) & ~(size_t)255;
        return p;
    };
    ushort* params  = (ushort*)alloc((size_t)127617 * 2);
    ushort* x_c     = (ushort*)alloc((size_t)N_NODES * IN_DIM * 2);
    int*    row_ptr = (int*)alloc((size_t)(N_NODES + 1) * 4);
    int*    rowcur  = (int*)alloc((size_t)N_NODES * 4);
    int*    deg     = (int*)alloc((size_t)N_NODES * 4);
    int*    colbuf  = (int*)alloc((size_t)EP_EDGES * 4);
    int*    bsum    = (int*)alloc(64 * 4);
    ushort* xl1     = (ushort*)alloc((size_t)N_NODES * C1 * 2);
    ushort* xr1     = (ushort*)alloc((size_t)N_NODES * C1 * 2);
    ushort* xskip   = (ushort*)alloc((size_t)N_NODES * HID * 2);
    ushort* h1      = (ushort*)alloc((size_t)N_NODES * C1 * 2);
    ushort* xl2     = (ushort*)alloc((size_t)N_NODES * HID * 2);
    ushort* xr2     = (ushort*)alloc((size_t)N_NODES * HID * 2);
    ushort* swzWl1  = (ushort*)alloc((size_t)IN_DIM * C1 * 2);
    ushort* swzWr1  = (ushort*)alloc((size_t)IN_DIM * C1 * 2);
    ushort* swzWs   = (ushort*)alloc((size_t)IN_DIM * HID * 2);
    ushort* swzWl2  = (ushort*)alloc((size_t)C1 * HID * 2);
    ushort* swzWr2  = (ushort*)alloc((size_t)C1 * HID * 2);

    ushort* bl1c   = params + 40960;
    ushort* br1c   = params + 82176;
    ushort* att1c  = params + 82432;
    ushort* bias1c = params + 82688;
    ushort* g1c    = params + 82944;
    ushort* b1c    = params + 83200;
    ushort* m1c    = params + 83456;
    ushort* v1c    = params + 83712;
    ushort* bl2c   = params + 100352;
    ushort* br2c   = params + 116800;
    ushort* att2c  = params + 116864;
    ushort* bias2c = params + 116928;
    ushort* g2c    = params + 116992;
    ushort* b2c    = params + 117056;
    ushort* m2c    = params + 117120;
    ushort* v2c    = params + 117184;
    ushort* bsc    = params + 127488;
    ushort* Woc    = params + 127552;
    ushort* boc    = params + 127616;

    // ---- canonicalize x (self-detecting), swizzle weights + small params ----
    cvt_x_k<<<(N_NODES * IN_DIM + 255) / 256, 256, 0, stream>>>(d_in[0], x_c, deg);

    SW2 sw;
    sw.W[0] = d_in[2];  sw.D[0] = swzWl1; sw.NT[0] = 16; sw.base[0] = 0;      // Wl1
    sw.W[1] = d_in[4];  sw.D[1] = swzWr1; sw.NT[1] = 16; sw.base[1] = 5120;   // Wr1
    sw.W[2] = d_in[22]; sw.D[2] = swzWs;  sw.NT[2] = 4;  sw.base[2] = 10240;  // Ws
    sw.W[3] = d_in[12]; sw.D[3] = swzWl2; sw.NT[3] = 4;  sw.base[3] = 11520;  // Wl2
    sw.W[4] = d_in[14]; sw.D[4] = swzWr2; sw.NT[4] = 4;  sw.base[4] = 13568;  // Wr2
    const int spidx[19] = {3,5,6,7,8,9,10,11, 13,15,16,17,18,19,20,21, 23,24, 25};
    for (int i = 0; i < 19; ++i) sw.sp[i] = d_in[spidx[i]];
    sw.xraw = d_in[0];
    swzp_k<<<62, 256, 0, stream>>>(sw, params);

    const int NB_N = (N_NODES + 255) / 256;        // 196
    const int NB_E = (EP_EDGES + 255) / 256;       // 3321
    const int NB_S = (N_NODES + 1023) / 1024;      // 49

    // ---- CSR build (reads raw edge_index, self-probing) ----
    const int* ei_raw = (const int*)d_in[1];
    hist_k<<<NB_E, 256, 0, stream>>>(ei_raw, deg);
    scan1_k<<<NB_S, 1024, 0, stream>>>(deg, row_ptr, bsum);
    scan3_k<<<NB_N, 256, 0, stream>>>(row_ptr, bsum, rowcur);
    scatter_k<<<NB_E, 256, 0, stream>>>(ei_raw, rowcur, colbuf);

    // ---- layer-1 linear transforms (+ skip), fused MFMA (split-N, 2 row-tiles/wave) ----
    gemm3_k<<<dim3((N_NODES + 127) / 128, 2), 256, 0, stream>>>(
        x_c, swzWl1, swzWr1, swzWs, bl1c, br1c, bsc, xl1, xr1, xskip, N_NODES);

    // ---- conv1 edge aggregation + BN1 + relu ----
    conv1_k<<<N_NODES, 256, 0, stream>>>(xl1, xr1, row_ptr, colbuf, att1c, bias1c,
                                         g1c, b1c, m1c, v1c, h1);

    // ---- layer-2 linear transforms, fused MFMA (2 row-tiles/wave) ----
    gemm2_k<<<(N_NODES + 127) / 128, 256, 0, stream>>>(h1, swzWl2, swzWr2, bl2c, br2c,
                                                       xl2, xr2, N_NODES);

    // ---- conv2 + BN2 + relu + skip + output linear ----
    conv2_k<<<(N_NODES + 3) / 4, 256, 0, stream>>>(xl2, xr2, xskip, row_ptr, colbuf,
                                                   att2c, bias2c, g2c, b2c, m2c, v2c,
                                                   Woc, boc, d_out, (const ushort*)d_in[0]);
}

// Round 12
// 421.407 us; speedup vs baseline: 1.0694x; 1.0081x over previous
//
#include <hip/hip_runtime.h>
#include <hip/hip_bf16.h>

#define N_NODES 50000
#define E_EDGES 800000
#define EP_EDGES 850000   // E + N self loops
#define IN_DIM 160
#define HEADS 4
#define HID 64
#define C1 256            // HEADS*HID
#define NEG_SLOPE 0.2f
#define BN_EPS 1e-5f

typedef __attribute__((ext_vector_type(8))) short bf16x8;
typedef __attribute__((ext_vector_type(4))) float f32x4;

__device__ __forceinline__ float b2f(ushort u) {
    return __uint_as_float(((unsigned)u) << 16);
}
__device__ __forceinline__ ushort f2b(float f) {
    __hip_bfloat16 h = __float2bfloat16(f);
    return *reinterpret_cast<ushort*>(&h);
}
__device__ __forceinline__ float lo16(uint u) { return __uint_as_float(u << 16); }
__device__ __forceinline__ float hi16(uint u) { return __uint_as_float(u & 0xffff0000u); }

// ---- in-kernel dtype probes (wave-wide, 1 read + ballot) ----
__device__ __forceinline__ bool probe_f32(const ushort* xraw) {
    int lane = threadIdx.x & 63;
    float a = fabsf(b2f(xraw[2 * lane]));
    unsigned long long m = __ballot(a > 1e-6f && a < 1e6f);
    return __popcll(m) < 48;
}
__device__ __forceinline__ bool probe_i64(const int* eraw) {
    int lane = threadIdx.x & 63;
    unsigned long long m = __ballot(eraw[2 * lane + 1] != 0);
    return __popcll(m) < 8;
}

// DPP-based add of a permuted copy: pure VALU pipe
template<int CTRL>
__device__ __forceinline__ float dpp_add(float p) {
    int t = __builtin_amdgcn_update_dpp(0, __float_as_int(p), CTRL, 0xf, 0xf, true);
    return p + __int_as_float(t);
}
// sum over each 16-lane row; all 16 lanes get the row total
__device__ __forceinline__ float row16_sum(float p) {
    p = dpp_add<0xB1>(p);    // quad_perm xor1
    p = dpp_add<0x4E>(p);    // quad_perm xor2
    p = dpp_add<0x124>(p);   // row_ror:4
    p = dpp_add<0x128>(p);   // row_ror:8
    return p;
}

// ---------------- fused front-end: cvt_x | weight swizzle + params | hist ----------------
// deg must be zeroed (hipMemsetAsync) before this kernel.
#define NB_CVT 31250   // 8,000,000 / 256
#define NB_SWZ 62
#define NB_HIST 3321

struct SW2 {
    const void* W[5];    // raw Wl1, Wr1, Ws, Wl2, Wr2
    ushort* D[5];
    int NT[5];
    int base[5];
    const void* sp[19];  // raw small tensors
};

__global__ void front_k(const void* __restrict__ xraw, ushort* __restrict__ x_c,
                        const int* __restrict__ ei, int* __restrict__ deg,
                        SW2 s, ushort* __restrict__ params) {
    const int b = blockIdx.x;
    if (b < NB_CVT) {
        const bool f32 = probe_f32((const ushort*)xraw);
        int i = b * 256 + threadIdx.x;           // < 8,000,000 exactly
        x_c[i] = f32 ? f2b(((const float*)xraw)[i]) : ((const ushort*)xraw)[i];
    } else if (b < NB_CVT + NB_SWZ) {
        const bool f32 = probe_f32((const ushort*)xraw);
        const int sb = b - NB_CVT;
        if (sb < 61) {
            int idx = sb * 256 + threadIdx.x;    // < 15616
            int seg = 0;
            #pragma unroll
            for (int k = 1; k < 5; ++k) seg += (idx >= s.base[k]) ? 1 : 0;
            int li = idx - s.base[seg];
            int NT = s.NT[seg];
            int N = NT << 4;
            int lane = li & 63;
            int ft = li >> 6;
            int kb = ft / NT, t = ft - kb * NT;
            int q = lane >> 4, m = lane & 15;
            const float* pf = (const float*)s.W[seg];
            const ushort* pu = (const ushort*)s.W[seg];
            ushort* d = s.D[seg] + (size_t)li * 8;
            #pragma unroll
            for (int j = 0; j < 8; ++j) {
                size_t src = (size_t)(kb * 32 + q * 8 + j) * N + t * 16 + m;
                d[j] = f32 ? f2b(pf[src]) : pu[src];
            }
        } else {
            const int SZ[19] = {256,256,256,256,256,256,256,256,
                                64,64,64,64,64,64,64,64,64,64, 1};
            const int OF[19] = {40960,82176,82432,82688,82944,83200,83456,83712,
                                100352,116800,116864,116928,116992,117056,117120,117184,
                                127488,127552, 127616};
            for (int e = threadIdx.x; e < 2689; e += 256) {
                int rem = e, t = 0;
                while (rem >= SZ[t]) { rem -= SZ[t]; ++t; }
                const float* pf = (const float*)s.sp[t];
                const ushort* pu = (const ushort*)s.sp[t];
                params[OF[t] + rem] = f32 ? f2b(pf[rem]) : pu[rem];
            }
        }
    } else {
        const bool i64 = probe_i64(ei);
        int e = (b - NB_CVT - NB_SWZ) * 256 + threadIdx.x;
        if (e >= EP_EDGES) return;
        int dst;
        if (e < E_EDGES) {
            int idx = E_EDGES + e;
            dst = i64 ? ei[2 * idx] : ei[idx];
        } else dst = e - E_EDGES;
        atomicAdd(&deg[dst], 1);
    }
}

// ---------------- block scan via wave shfl + LDS (2 barriers) ----------------
__global__ __launch_bounds__(1024) void scan1_k(const int* __restrict__ deg,
                                                int* __restrict__ exc,
                                                int* __restrict__ bsum) {
    __shared__ int wsum[16];
    const int t = threadIdx.x;
    const int lane = t & 63, w = t >> 6;
    int i = blockIdx.x * 1024 + t;
    int v = (i < N_NODES) ? deg[i] : 0;
    int sIncl = v;
    #pragma unroll
    for (int d = 1; d < 64; d <<= 1) {
        int u = __shfl_up(sIncl, d);
        if (lane >= d) sIncl += u;
    }
    if (lane == 63) wsum[w] = sIncl;
    __syncthreads();
    if (w == 0) {
        int p = (lane < 16) ? wsum[lane] : 0;
        #pragma unroll
        for (int d = 1; d < 16; d <<= 1) {
            int u = __shfl_up(p, d);
            if (lane >= d) p += u;
        }
        if (lane < 16) wsum[lane] = p;
    }
    __syncthreads();
    int base = (w > 0) ? wsum[w - 1] : 0;
    int incl = base + sIncl;
    if (i < N_NODES) exc[i] = incl - v;
    if (t == 1023) bsum[blockIdx.x] = incl;
}

// scan3 folds the tiny scan of block sums
__global__ void scan3_k(int* __restrict__ row_ptr, const int* __restrict__ bsum,
                        int* __restrict__ rowcur) {
    const int chunk = blockIdx.x >> 2;
    const int lane = threadIdx.x & 63;
    int v = (lane < chunk) ? bsum[lane] : 0;   // chunk <= 48 < 64
    #pragma unroll
    for (int d = 32; d > 0; d >>= 1) v += __shfl_xor(v, d);
    int i = blockIdx.x * 256 + threadIdx.x;
    if (i >= N_NODES) return;
    int rp = row_ptr[i] + v;
    row_ptr[i] = rp;
    rowcur[i] = rp;
    if (i == 0) row_ptr[N_NODES] = EP_EDGES;
}

__global__ void scatter_k(const int* __restrict__ ei,
                          int* __restrict__ rowcur, int* __restrict__ col) {
    const bool i64 = probe_i64(ei);
    int e = blockIdx.x * 256 + threadIdx.x;
    if (e >= EP_EDGES) return;
    int src, dst;
    if (e < E_EDGES) {
        if (i64) { src = ei[2 * e]; dst = ei[2 * (E_EDGES + e)]; }
        else     { src = ei[e];     dst = ei[E_EDGES + e]; }
    } else { src = e - E_EDGES; dst = src; }
    int pos = atomicAdd(&rowcur[dst], 1);
    col[pos] = src;
}

// ---------------- fused layer-1 MFMA GEMM, split-N, 2 row-tiles/wave ----------------
__global__ __launch_bounds__(256) void gemm3_k(const ushort* __restrict__ A,
                                               const ushort* __restrict__ B1,
                                               const ushort* __restrict__ B2,
                                               const ushort* __restrict__ B3,
                                               const ushort* __restrict__ bi1,
                                               const ushort* __restrict__ bi2,
                                               const ushort* __restrict__ bi3,
                                               ushort* __restrict__ o1,
                                               ushort* __restrict__ o2,
                                               ushort* __restrict__ o3,
                                               int M) {
    const int wave = threadIdx.x >> 6;
    const int lane = threadIdx.x & 63;
    const int ch = blockIdx.y;
    const int row0 = blockIdx.x * 128 + wave * 32;
    if (row0 >= M) return;
    int ar0 = row0 + (lane & 15);      if (ar0 >= M) ar0 = M - 1;
    int ar1 = row0 + 16 + (lane & 15); if (ar1 >= M) ar1 = M - 1;
    const ushort* ap0 = A + (size_t)ar0 * IN_DIM + (lane >> 4) * 8;
    const ushort* ap1 = A + (size_t)ar1 * IN_DIM + (lane >> 4) * 8;
    bf16x8 af0[5], af1[5];
    #pragma unroll
    for (int kb = 0; kb < 5; ++kb) {
        af0[kb] = *(const bf16x8*)(ap0 + kb * 32);
        af1[kb] = *(const bf16x8*)(ap1 + kb * 32);
    }
    const bf16x8* b1 = (const bf16x8*)B1;
    const bf16x8* b2 = (const bf16x8*)B2;
    const bf16x8* b3 = (const bf16x8*)B3;
    f32x4 aL[2][8] = {}, aR[2][8] = {}, aS[2][2] = {};
    #pragma unroll
    for (int kb = 0; kb < 5; ++kb) {
        #pragma unroll
        for (int j = 0; j < 8; ++j) {
            bf16x8 b = b1[(kb * 16 + ch * 8 + j) * 64 + lane];
            aL[0][j] = __builtin_amdgcn_mfma_f32_16x16x32_bf16(af0[kb], b, aL[0][j], 0, 0, 0);
            aL[1][j] = __builtin_amdgcn_mfma_f32_16x16x32_bf16(af1[kb], b, aL[1][j], 0, 0, 0);
        }
        #pragma unroll
        for (int j = 0; j < 8; ++j) {
            bf16x8 b = b2[(kb * 16 + ch * 8 + j) * 64 + lane];
            aR[0][j] = __builtin_amdgcn_mfma_f32_16x16x32_bf16(af0[kb], b, aR[0][j], 0, 0, 0);
            aR[1][j] = __builtin_amdgcn_mfma_f32_16x16x32_bf16(af1[kb], b, aR[1][j], 0, 0, 0);
        }
        #pragma unroll
        for (int j = 0; j < 2; ++j) {
            bf16x8 b = b3[(kb * 4 + ch * 2 + j) * 64 + lane];
            aS[0][j] = __builtin_amdgcn_mfma_f32_16x16x32_bf16(af0[kb], b, aS[0][j], 0, 0, 0);
            aS[1][j] = __builtin_amdgcn_mfma_f32_16x16x32_bf16(af1[kb], b, aS[1][j], 0, 0, 0);
        }
    }
    const int cn = lane & 15, cq = lane >> 4;
    #pragma unroll
    for (int rt = 0; rt < 2; ++rt) {
        #pragma unroll
        for (int j = 0; j < 8; ++j) {
            int colc = (ch * 8 + j) * 16 + cn;
            float bbL = b2f(bi1[colc]);
            float bbR = b2f(bi2[colc]);
            #pragma unroll
            for (int r = 0; r < 4; ++r) {
                int grow = row0 + rt * 16 + cq * 4 + r;
                if (grow < M) {
                    o1[(size_t)grow * C1 + colc] = f2b(aL[rt][j][r] + bbL);
                    o2[(size_t)grow * C1 + colc] = f2b(aR[rt][j][r] + bbR);
                }
            }
        }
        #pragma unroll
        for (int j = 0; j < 2; ++j) {
            int colc = (ch * 2 + j) * 16 + cn;
            float bb = b2f(bi3[colc]);
            #pragma unroll
            for (int r = 0; r < 4; ++r) {
                int grow = row0 + rt * 16 + cq * 4 + r;
                if (grow < M)
                    o3[(size_t)grow * HID + colc] = f2b(aS[rt][j][r] + bb);
            }
        }
    }
}

// ---------------- fused layer-2 MFMA GEMM: xl2(64) + xr2(64), K=256 (round-9 form) ----------------
__global__ __launch_bounds__(256) void gemm2_k(const ushort* __restrict__ A,
                                               const ushort* __restrict__ B1,
                                               const ushort* __restrict__ B2,
                                               const ushort* __restrict__ bi1,
                                               const ushort* __restrict__ bi2,
                                               ushort* __restrict__ o1,
                                               ushort* __restrict__ o2,
                                               int M) {
    const int wave = threadIdx.x >> 6;
    const int lane = threadIdx.x & 63;
    const int row0 = blockIdx.x * 64 + wave * 16;
    if (row0 >= M) return;
    int arow = row0 + (lane & 15);
    if (arow >= M) arow = M - 1;
    const ushort* aptr = A + (size_t)arow * C1 + (lane >> 4) * 8;
    const bf16x8* b1 = (const bf16x8*)B1;
    const bf16x8* b2 = (const bf16x8*)B2;
    f32x4 aL[4] = {}, aR[4] = {};
    #pragma unroll
    for (int kb = 0; kb < 8; ++kb) {
        bf16x8 af = *(const bf16x8*)(aptr + kb * 32);
        #pragma unroll
        for (int t = 0; t < 4; ++t)
            aL[t] = __builtin_amdgcn_mfma_f32_16x16x32_bf16(af, b1[(kb * 4 + t) * 64 + lane], aL[t], 0, 0, 0);
        #pragma unroll
        for (int t = 0; t < 4; ++t)
            aR[t] = __builtin_amdgcn_mfma_f32_16x16x32_bf16(af, b2[(kb * 4 + t) * 64 + lane], aR[t], 0, 0, 0);
    }
    const int cn = lane & 15, cq = lane >> 4;
    #pragma unroll
    for (int t = 0; t < 4; ++t) {
        float bbL = b2f(bi1[t * 16 + cn]);
        float bbR = b2f(bi2[t * 16 + cn]);
        #pragma unroll
        for (int r = 0; r < 4; ++r) {
            int grow = row0 + cq * 4 + r;
            if (grow < M) {
                o1[(size_t)grow * HID + t * 16 + cn] = f2b(aL[t][r] + bbL);
                o2[(size_t)grow * HID + t * 16 + cn] = f2b(aR[t][r] + bbR);
            }
        }
    }
}

// ---------------- conv1: 4 gather chains, maskless full trips + guarded epilogue ----------------
__global__ __launch_bounds__(256) void conv1_k(const ushort* __restrict__ xl,
                                               const ushort* __restrict__ xr,
                                               const int* __restrict__ row_ptr,
                                               const int* __restrict__ col,
                                               const ushort* __restrict__ att,
                                               const ushort* __restrict__ bias1,
                                               const ushort* __restrict__ g1,
                                               const ushort* __restrict__ b1,
                                               const ushort* __restrict__ m1,
                                               const ushort* __restrict__ v1,
                                               ushort* __restrict__ h1out) {
    const int n = blockIdx.x;
    const int h = threadIdx.x >> 6;          // wave = head
    const int lane = threadIdx.x & 63;
    const int grp = lane >> 4;               // edge slot 0..3
    const int m = lane & 15;                 // channel quad
    const uint cpi = h * 16 + m;             // uint2 index within 64-uint2 row
    const uint2* xl2v = (const uint2*)xl;
    const uint2 xru = ((const uint2*)xr)[(size_t)n * 64 + cpi];
    const float xr0 = lo16(xru.x), xr1 = hi16(xru.x);
    const float xr2 = lo16(xru.y), xr3 = hi16(xru.y);
    const uint2 atu = ((const uint2*)att)[cpi];
    const float at0 = lo16(atu.x), at1 = hi16(atu.x);
    const float at2 = lo16(atu.y), at3 = hi16(atu.y);
    const int e0 = row_ptr[n], e1 = row_ptr[n + 1];
    const int deg = e1 - e0;
    const int iend = e0 + (deg & ~15);       // end of maskless full trips
    float a0 = 0.f, a1 = 0.f, a2 = 0.f, a3 = 0.f, den = 0.f;

    auto edge4 = [&](const uint2 xu, bool masked, int jbase) {
        const float x0 = lo16(xu.x), x1 = hi16(xu.x);
        const float x2 = lo16(xu.y), x3 = hi16(xu.y);
        float t0 = x0 + xr0; t0 = fmaxf(t0, t0 * NEG_SLOPE);
        float t1 = x1 + xr1; t1 = fmaxf(t1, t1 * NEG_SLOPE);
        float t2 = x2 + xr2; t2 = fmaxf(t2, t2 * NEG_SLOPE);
        float t3 = x3 + xr3; t3 = fmaxf(t3, t3 * NEG_SLOPE);
        float p = fmaf(t0, at0, fmaf(t1, at1, fmaf(t2, at2, t3 * at3)));
        p = row16_sum(p);
        float w;
        if (masked) {
            w = __expf(fminf(p, 60.f));
            w = ((jbase + grp) < e1) ? w : 0.f;
        } else {
            w = __expf(p);   // logits bounded; no clamp in hot path
        }
        a0 = fmaf(w, x0, a0); a1 = fmaf(w, x1, a1);
        a2 = fmaf(w, x2, a2); a3 = fmaf(w, x3, a3);
        den += w;
    };

    uint s0_, s1_, s2_, s3_;
    {
        const int j0 = e0 + grp, j1 = j0 + 4, j2 = j0 + 8, j3 = j0 + 12;
        s0_ = (uint)col[j0 < e1 ? j0 : e1 - 1];
        s1_ = (uint)col[j1 < e1 ? j1 : e1 - 1];
        s2_ = (uint)col[j2 < e1 ? j2 : e1 - 1];
        s3_ = (uint)col[j3 < e1 ? j3 : e1 - 1];
    }
    for (int i = e0; i < iend; i += 16) {
        const uint2 xu0 = xl2v[(s0_ << 6) + cpi];
        const uint2 xu1 = xl2v[(s1_ << 6) + cpi];
        const uint2 xu2 = xl2v[(s2_ << 6) + cpi];
        const uint2 xu3 = xl2v[(s3_ << 6) + cpi];
        const int j0 = i + 16 + grp, j1 = j0 + 4, j2 = j0 + 8, j3 = j0 + 12;
        s0_ = (uint)col[j0 < e1 ? j0 : e1 - 1];
        s1_ = (uint)col[j1 < e1 ? j1 : e1 - 1];
        s2_ = (uint)col[j2 < e1 ? j2 : e1 - 1];
        s3_ = (uint)col[j3 < e1 ? j3 : e1 - 1];
        edge4(xu0, false, 0);
        edge4(xu1, false, 0);
        edge4(xu2, false, 0);
        edge4(xu3, false, 0);
    }
    const int rem = e1 - iend;               // 0..15
    if (rem > 0) {
        const uint2 xu0 = xl2v[(s0_ << 6) + cpi];   // all 4 issued: MLP preserved
        const uint2 xu1 = xl2v[(s1_ << 6) + cpi];
        const uint2 xu2 = xl2v[(s2_ << 6) + cpi];
        const uint2 xu3 = xl2v[(s3_ << 6) + cpi];
        edge4(xu0, true, iend);
        if (rem > 4)  edge4(xu1, true, iend + 4);
        if (rem > 8)  edge4(xu2, true, iend + 8);
        if (rem > 12) edge4(xu3, true, iend + 12);
    }
    a0 += __shfl_xor(a0, 16); a0 += __shfl_xor(a0, 32);
    a1 += __shfl_xor(a1, 16); a1 += __shfl_xor(a1, 32);
    a2 += __shfl_xor(a2, 16); a2 += __shfl_xor(a2, 32);
    a3 += __shfl_xor(a3, 16); a3 += __shfl_xor(a3, 32);
    den += __shfl_xor(den, 16); den += __shfl_xor(den, 32);
    if (lane < 16) {
        const float inv = 1.f / den;
        const uint2 biu = ((const uint2*)bias1)[cpi];
        const uint2 gu  = ((const uint2*)g1)[cpi];
        const uint2 bu  = ((const uint2*)b1)[cpi];
        const uint2 mu  = ((const uint2*)m1)[cpi];
        const uint2 vu  = ((const uint2*)v1)[cpi];
        float o0 = fmaf(a0, inv, lo16(biu.x));
        float o1 = fmaf(a1, inv, hi16(biu.x));
        float o2 = fmaf(a2, inv, lo16(biu.y));
        float o3 = fmaf(a3, inv, hi16(biu.y));
        float s0 = lo16(gu.x) * rsqrtf(lo16(vu.x) + BN_EPS);
        float s1 = hi16(gu.x) * rsqrtf(hi16(vu.x) + BN_EPS);
        float s2 = lo16(gu.y) * rsqrtf(lo16(vu.y) + BN_EPS);
        float s3 = hi16(gu.y) * rsqrtf(hi16(vu.y) + BN_EPS);
        float h0 = fmaxf((o0 - lo16(mu.x)) * s0 + lo16(bu.x), 0.f);
        float h1v = fmaxf((o1 - hi16(mu.x)) * s1 + hi16(bu.x), 0.f);
        float h2 = fmaxf((o2 - lo16(mu.y)) * s2 + lo16(bu.y), 0.f);
        float h3 = fmaxf((o3 - hi16(mu.y)) * s3 + hi16(bu.y), 0.f);
        uint2 ou;
        ou.x = (uint)f2b(h0) | ((uint)f2b(h1v) << 16);
        ou.y = (uint)f2b(h2) | ((uint)f2b(h3) << 16);
        ((uint2*)h1out)[(size_t)n * 64 + cpi] = ou;
    }
}

// ---------------- conv2 + BN2 + relu + skip + output linear ----------------
__global__ __launch_bounds__(256) void conv2_k(const ushort* __restrict__ xl,
                                               const ushort* __restrict__ xr,
                                               const ushort* __restrict__ xskip,
                                               const int* __restrict__ row_ptr,
                                               const int* __restrict__ col,
                                               const ushort* __restrict__ att2,
                                               const ushort* __restrict__ bias2,
                                               const ushort* __restrict__ g2,
                                               const ushort* __restrict__ bb2,
                                               const ushort* __restrict__ m2,
                                               const ushort* __restrict__ v2,
                                               const ushort* __restrict__ Wo,
                                               const ushort* __restrict__ bo,
                                               void* __restrict__ out,
                                               const ushort* __restrict__ xraw) {
    const bool f32out = probe_f32(xraw);
    const int n = blockIdx.x * 4 + (threadIdx.x >> 6);
    if (n >= N_NODES) return;
    const int lane = threadIdx.x & 63;
    const int grp = lane >> 4;
    const uint m = lane & 15;                // uint2 index within 16-uint2 row
    const uint2* xl2v = (const uint2*)xl;
    const uint2 xru = ((const uint2*)xr)[(size_t)n * 16 + m];
    const float xr0 = lo16(xru.x), xr1 = hi16(xru.x);
    const float xr2 = lo16(xru.y), xr3 = hi16(xru.y);
    const uint2 atu = ((const uint2*)att2)[m];
    const float at0 = lo16(atu.x), at1 = hi16(atu.x);
    const float at2 = lo16(atu.y), at3 = hi16(atu.y);
    const int e0 = row_ptr[n], e1 = row_ptr[n + 1];
    const int deg = e1 - e0;
    const int iend = e0 + (deg & ~15);
    float a0 = 0.f, a1 = 0.f, a2 = 0.f, a3 = 0.f, den = 0.f;

    auto edge4 = [&](const uint2 xu, bool masked, int jbase) {
        const float x0 = lo16(xu.x), x1 = hi16(xu.x);
        const float x2 = lo16(xu.y), x3 = hi16(xu.y);
        float t0 = x0 + xr0; t0 = fmaxf(t0, t0 * NEG_SLOPE);
        float t1 = x1 + xr1; t1 = fmaxf(t1, t1 * NEG_SLOPE);
        float t2 = x2 + xr2; t2 = fmaxf(t2, t2 * NEG_SLOPE);
        float t3 = x3 + xr3; t3 = fmaxf(t3, t3 * NEG_SLOPE);
        float p = fmaf(t0, at0, fmaf(t1, at1, fmaf(t2, at2, t3 * at3)));
        p = row16_sum(p);
        float w;
        if (masked) {
            w = __expf(fminf(p, 60.f));
            w = ((jbase + grp) < e1) ? w : 0.f;
        } else {
            w = __expf(p);
        }
        a0 = fmaf(w, x0, a0); a1 = fmaf(w, x1, a1);
        a2 = fmaf(w, x2, a2); a3 = fmaf(w, x3, a3);
        den += w;
    };

    uint s0_, s1_, s2_, s3_;
    {
        const int j0 = e0 + grp, j1 = j0 + 4, j2 = j0 + 8, j3 = j0 + 12;
        s0_ = (uint)col[j0 < e1 ? j0 : e1 - 1];
        s1_ = (uint)col[j1 < e1 ? j1 : e1 - 1];
        s2_ = (uint)col[j2 < e1 ? j2 : e1 - 1];
        s3_ = (uint)col[j3 < e1 ? j3 : e1 - 1];
    }
    for (int i = e0; i < iend; i += 16) {
        const uint2 xu0 = xl2v[(s0_ << 4) + m];
        const uint2 xu1 = xl2v[(s1_ << 4) + m];
        const uint2 xu2 = xl2v[(s2_ << 4) + m];
        const uint2 xu3 = xl2v[(s3_ << 4) + m];
        const int j0 = i + 16 + grp, j1 = j0 + 4, j2 = j0 + 8, j3 = j0 + 12;
        s0_ = (uint)col[j0 < e1 ? j0 : e1 - 1];
        s1_ = (uint)col[j1 < e1 ? j1 : e1 - 1];
        s2_ = (uint)col[j2 < e1 ? j2 : e1 - 1];
        s3_ = (uint)col[j3 < e1 ? j3 : e1 - 1];
        edge4(xu0, false, 0);
        edge4(xu1, false, 0);
        edge4(xu2, false, 0);
        edge4(xu3, false, 0);
    }
    const int rem = e1 - iend;
    if (rem > 0) {
        const uint2 xu0 = xl2v[(s0_ << 4) + m];
        const uint2 xu1 = xl2v[(s1_ << 4) + m];
        const uint2 xu2 = xl2v[(s2_ << 4) + m];
        const uint2 xu3 = xl2v[(s3_ << 4) + m];
        edge4(xu0, true, iend);
        if (rem > 4)  edge4(xu1, true, iend + 4);
        if (rem > 8)  edge4(xu2, true, iend + 8);
        if (rem > 12) edge4(xu3, true, iend + 12);
    }
    a0 += __shfl_xor(a0, 16); a0 += __shfl_xor(a0, 32);
    a1 += __shfl_xor(a1, 16); a1 += __shfl_xor(a1, 32);
    a2 += __shfl_xor(a2, 16); a2 += __shfl_xor(a2, 32);
    a3 += __shfl_xor(a3, 16); a3 += __shfl_xor(a3, 32);
    den += __shfl_xor(den, 16); den += __shfl_xor(den, 32);
    if (lane < 16) {
        const float inv = 1.f / den;
        const uint2 biu = ((const uint2*)bias2)[m];
        const uint2 gu  = ((const uint2*)g2)[m];
        const uint2 bu  = ((const uint2*)bb2)[m];
        const uint2 mu  = ((const uint2*)m2)[m];
        const uint2 vu  = ((const uint2*)v2)[m];
        const uint2 sku = ((const uint2*)xskip)[(size_t)n * 16 + m];
        const uint2 wou = ((const uint2*)Wo)[m];
        float o0 = fmaf(a0, inv, lo16(biu.x));
        float o1 = fmaf(a1, inv, hi16(biu.x));
        float o2 = fmaf(a2, inv, lo16(biu.y));
        float o3 = fmaf(a3, inv, hi16(biu.y));
        float s0 = lo16(gu.x) * rsqrtf(lo16(vu.x) + BN_EPS);
        float s1 = hi16(gu.x) * rsqrtf(hi16(vu.x) + BN_EPS);
        float s2 = lo16(gu.y) * rsqrtf(lo16(vu.y) + BN_EPS);
        float s3 = hi16(gu.y) * rsqrtf(hi16(vu.y) + BN_EPS);
        float h0 = fmaxf((o0 - lo16(mu.x)) * s0 + lo16(bu.x), 0.f) + lo16(sku.x);
        float h1v = fmaxf((o1 - hi16(mu.x)) * s1 + hi16(bu.x), 0.f) + hi16(sku.x);
        float h2 = fmaxf((o2 - lo16(mu.y)) * s2 + lo16(bu.y), 0.f) + lo16(sku.y);
        float h3 = fmaxf((o3 - hi16(mu.y)) * s3 + hi16(bu.y), 0.f) + hi16(sku.y);
        float d = fmaf(h0, lo16(wou.x), fmaf(h1v, hi16(wou.x),
                  fmaf(h2, lo16(wou.y), h3 * hi16(wou.y))));
        d = row16_sum(d);
        if (m == 0) {
            float r = d + b2f(bo[0]);
            if (f32out) ((float*)out)[n] = r;
            else        ((ushort*)out)[n] = f2b(r);
        }
    }
}

extern "C" void kernel_launch(void* const* d_in, const int* in_sizes, int n_in,
                              void* d_out, int out_size, void* d_ws, size_t ws_size,
                              hipStream_t stream) {
    char* ws = (char*)d_ws;
    size_t off = 0;
    auto alloc = [&](size_t bytes) -> void* {
        void* p = ws + off;
        off += (bytes + 255) & ~(size_t)255;
        return p;
    };
    ushort* params  = (ushort*)alloc((size_t)127617 * 2);
    ushort* x_c     = (ushort*)alloc((size_t)N_NODES * IN_DIM * 2);
    int*    row_ptr = (int*)alloc((size_t)(N_NODES + 1) * 4);
    int*    rowcur  = (int*)alloc((size_t)N_NODES * 4);
    int*    deg     = (int*)alloc((size_t)N_NODES * 4);
    int*    colbuf  = (int*)alloc((size_t)EP_EDGES * 4);
    int*    bsum    = (int*)alloc(64 * 4);
    ushort* xl1     = (ushort*)alloc((size_t)N_NODES * C1 * 2);
    ushort* xr1     = (ushort*)alloc((size_t)N_NODES * C1 * 2);
    ushort* xskip   = (ushort*)alloc((size_t)N_NODES * HID * 2);
    ushort* h1      = (ushort*)alloc((size_t)N_NODES * C1 * 2);
    ushort* xl2     = (ushort*)alloc((size_t)N_NODES * HID * 2);
    ushort* xr2     = (ushort*)alloc((size_t)N_NODES * HID * 2);
    ushort* swzWl1  = (ushort*)alloc((size_t)IN_DIM * C1 * 2);
    ushort* swzWr1  = (ushort*)alloc((size_t)IN_DIM * C1 * 2);
    ushort* swzWs   = (ushort*)alloc((size_t)IN_DIM * HID * 2);
    ushort* swzWl2  = (ushort*)alloc((size_t)C1 * HID * 2);
    ushort* swzWr2  = (ushort*)alloc((size_t)C1 * HID * 2);

    ushort* bl1c   = params + 40960;
    ushort* br1c   = params + 82176;
    ushort* att1c  = params + 82432;
    ushort* bias1c = params + 82688;
    ushort* g1c    = params + 82944;
    ushort* b1c    = params + 83200;
    ushort* m1c    = params + 83456;
    ushort* v1c    = params + 83712;
    ushort* bl2c   = params + 100352;
    ushort* br2c   = params + 116800;
    ushort* att2c  = params + 116864;
    ushort* bias2c = params + 116928;
    ushort* g2c    = params + 116992;
    ushort* b2c    = params + 117056;
    ushort* m2c    = params + 117120;
    ushort* v2c    = params + 117184;
    ushort* bsc    = params + 127488;
    ushort* Woc    = params + 127552;
    ushort* boc    = params + 127616;

    const int* ei_raw = (const int*)d_in[1];

    // ---- deg = 0 (needed by fused hist) ----
    hipMemsetAsync(deg, 0, (size_t)N_NODES * 4, stream);

    // ---- fused front-end: cvt_x | swizzle+params | hist ----
    SW2 sw;
    sw.W[0] = d_in[2];  sw.D[0] = swzWl1; sw.NT[0] = 16; sw.base[0] = 0;      // Wl1
    sw.W[1] = d_in[4];  sw.D[1] = swzWr1; sw.NT[1] = 16; sw.base[1] = 5120;   // Wr1
    sw.W[2] = d_in[22]; sw.D[2] = swzWs;  sw.NT[2] = 4;  sw.base[2] = 10240;  // Ws
    sw.W[3] = d_in[12]; sw.D[3] = swzWl2; sw.NT[3] = 4;  sw.base[3] = 11520;  // Wl2
    sw.W[4] = d_in[14]; sw.D[4] = swzWr2; sw.NT[4] = 4;  sw.base[4] = 13568;  // Wr2
    const int spidx[19] = {3,5,6,7,8,9,10,11, 13,15,16,17,18,19,20,21, 23,24, 25};
    for (int i = 0; i < 19; ++i) sw.sp[i] = d_in[spidx[i]];
    front_k<<<NB_CVT + NB_SWZ + NB_HIST, 256, 0, stream>>>(d_in[0], x_c, ei_raw, deg,
                                                           sw, params);

    const int NB_N = (N_NODES + 255) / 256;        // 196
    const int NB_E = (EP_EDGES + 255) / 256;       // 3321
    const int NB_S = (N_NODES + 1023) / 1024;      // 49

    // ---- CSR scan + scatter ----
    scan1_k<<<NB_S, 1024, 0, stream>>>(deg, row_ptr, bsum);
    scan3_k<<<NB_N, 256, 0, stream>>>(row_ptr, bsum, rowcur);
    scatter_k<<<NB_E, 256, 0, stream>>>(ei_raw, rowcur, colbuf);

    // ---- layer-1 linear transforms (+ skip), fused MFMA (split-N, 2 row-tiles/wave) ----
    gemm3_k<<<dim3((N_NODES + 127) / 128, 2), 256, 0, stream>>>(
        x_c, swzWl1, swzWr1, swzWs, bl1c, br1c, bsc, xl1, xr1, xskip, N_NODES);

    // ---- conv1 edge aggregation + BN1 + relu ----
    conv1_k<<<N_NODES, 256, 0, stream>>>(xl1, xr1, row_ptr, colbuf, att1c, bias1c,
                                         g1c, b1c, m1c, v1c, h1);

    // ---- layer-2 linear transforms, fused MFMA ----
    gemm2_k<<<(N_NODES + 63) / 64, 256, 0, stream>>>(h1, swzWl2, swzWr2, bl2c, br2c,
                                                     xl2, xr2, N_NODES);

    // ---- conv2 + BN2 + relu + skip + output linear ----
    conv2_k<<<(N_NODES + 3) / 4, 256, 0, stream>>>(xl2, xr2, xskip, row_ptr, colbuf,
                                                   att2c, bias2c, g2c, b2c, m2c, v2c,
                                                   Woc, boc, d_out, (const ushort*)d_in[0]);
}

// Round 13
// 397.499 us; speedup vs baseline: 1.1337x; 1.0601x over previous
//
#include <hip/hip_runtime.h>
#include <hip/hip_bf16.h>

#define N_NODES 50000
#define E_EDGES 800000
#define EP_EDGES 850000   // E + N self loops
#define IN_DIM 160
#define HEADS 4
#define HID 64
#define C1 256            // HEADS*HID
#define NEG_SLOPE 0.2f
#define BN_EPS 1e-5f

typedef __attribute__((ext_vector_type(8))) short bf16x8;
typedef __attribute__((ext_vector_type(4))) float f32x4;

__device__ __forceinline__ float b2f(ushort u) {
    return __uint_as_float(((unsigned)u) << 16);
}
__device__ __forceinline__ ushort f2b(float f) {
    __hip_bfloat16 h = __float2bfloat16(f);
    return *reinterpret_cast<ushort*>(&h);
}
__device__ __forceinline__ float lo16(uint u) { return __uint_as_float(u << 16); }
__device__ __forceinline__ float hi16(uint u) { return __uint_as_float(u & 0xffff0000u); }

// ---- in-kernel dtype probes (wave-wide, 1 read + ballot) ----
__device__ __forceinline__ bool probe_f32(const ushort* xraw) {
    int lane = threadIdx.x & 63;
    float a = fabsf(b2f(xraw[2 * lane]));
    unsigned long long m = __ballot(a > 1e-6f && a < 1e6f);
    return __popcll(m) < 48;
}
__device__ __forceinline__ bool probe_i64(const int* eraw) {
    int lane = threadIdx.x & 63;
    unsigned long long m = __ballot(eraw[2 * lane + 1] != 0);
    return __popcll(m) < 8;
}

// DPP-based add of a permuted copy: pure VALU pipe
template<int CTRL>
__device__ __forceinline__ float dpp_add(float p) {
    int t = __builtin_amdgcn_update_dpp(0, __float_as_int(p), CTRL, 0xf, 0xf, true);
    return p + __int_as_float(t);
}
// sum over each 16-lane row; all 16 lanes get the row total
__device__ __forceinline__ float row16_sum(float p) {
    p = dpp_add<0xB1>(p);    // quad_perm xor1
    p = dpp_add<0x4E>(p);    // quad_perm xor2
    p = dpp_add<0x124>(p);   // row_ror:4
    p = dpp_add<0x128>(p);   // row_ror:8
    return p;
}

// ---------------- fused front-end: weight swizzle + params | hist(+epos) ----------------
// deg must be zeroed (hipMemsetAsync) before this kernel.
#define NB_SWZ 62
#define NB_HIST 3321

struct SW2 {
    const void* W[5];    // raw Wl1, Wr1, Ws, Wl2, Wr2
    ushort* D[5];
    int NT[5];
    int base[5];
    const void* sp[19];  // raw small tensors
    const void* xraw;
};

__global__ void front_k(const int* __restrict__ ei, int* __restrict__ deg,
                        int* __restrict__ epos, SW2 s, ushort* __restrict__ params) {
    const int b = blockIdx.x;
    if (b < NB_SWZ) {
        const bool f32 = probe_f32((const ushort*)s.xraw);
        if (b < 61) {
            int idx = b * 256 + threadIdx.x;     // < 15616
            int seg = 0;
            #pragma unroll
            for (int k = 1; k < 5; ++k) seg += (idx >= s.base[k]) ? 1 : 0;
            int li = idx - s.base[seg];
            int NT = s.NT[seg];
            int N = NT << 4;
            int lane = li & 63;
            int ft = li >> 6;
            int kb = ft / NT, t = ft - kb * NT;
            int q = lane >> 4, m = lane & 15;
            const float* pf = (const float*)s.W[seg];
            const ushort* pu = (const ushort*)s.W[seg];
            ushort* d = s.D[seg] + (size_t)li * 8;
            #pragma unroll
            for (int j = 0; j < 8; ++j) {
                size_t src = (size_t)(kb * 32 + q * 8 + j) * N + t * 16 + m;
                d[j] = f32 ? f2b(pf[src]) : pu[src];
            }
        } else {
            const int SZ[19] = {256,256,256,256,256,256,256,256,
                                64,64,64,64,64,64,64,64,64,64, 1};
            const int OF[19] = {40960,82176,82432,82688,82944,83200,83456,83712,
                                100352,116800,116864,116928,116992,117056,117120,117184,
                                127488,127552, 127616};
            for (int e = threadIdx.x; e < 2689; e += 256) {
                int rem = e, t = 0;
                while (rem >= SZ[t]) { rem -= SZ[t]; ++t; }
                const float* pf = (const float*)s.sp[t];
                const ushort* pu = (const ushort*)s.sp[t];
                params[OF[t] + rem] = f32 ? f2b(pf[rem]) : pu[rem];
            }
        }
    } else {
        const bool i64 = probe_i64(ei);
        int e = (b - NB_SWZ) * 256 + threadIdx.x;
        if (e >= EP_EDGES) return;
        int dst;
        if (e < E_EDGES) {
            int idx = E_EDGES + e;
            dst = i64 ? ei[2 * idx] : ei[idx];
        } else dst = e - E_EDGES;
        epos[e] = atomicAdd(&deg[dst], 1);   // slot within node; reused by scatter
    }
}

// ---------------- block scan via wave shfl + LDS (2 barriers) ----------------
__global__ __launch_bounds__(1024) void scan1_k(const int* __restrict__ deg,
                                                int* __restrict__ exc,
                                                int* __restrict__ bsum) {
    __shared__ int wsum[16];
    const int t = threadIdx.x;
    const int lane = t & 63, w = t >> 6;
    int i = blockIdx.x * 1024 + t;
    int v = (i < N_NODES) ? deg[i] : 0;
    int sIncl = v;
    #pragma unroll
    for (int d = 1; d < 64; d <<= 1) {
        int u = __shfl_up(sIncl, d);
        if (lane >= d) sIncl += u;
    }
    if (lane == 63) wsum[w] = sIncl;
    __syncthreads();
    if (w == 0) {
        int p = (lane < 16) ? wsum[lane] : 0;
        #pragma unroll
        for (int d = 1; d < 16; d <<= 1) {
            int u = __shfl_up(p, d);
            if (lane >= d) p += u;
        }
        if (lane < 16) wsum[lane] = p;
    }
    __syncthreads();
    int base = (w > 0) ? wsum[w - 1] : 0;
    int incl = base + sIncl;
    if (i < N_NODES) exc[i] = incl - v;
    if (t == 1023) bsum[blockIdx.x] = incl;
}

// scan3 folds the tiny scan of block sums
__global__ void scan3_k(int* __restrict__ row_ptr, const int* __restrict__ bsum) {
    const int chunk = blockIdx.x >> 2;
    const int lane = threadIdx.x & 63;
    int v = (lane < chunk) ? bsum[lane] : 0;   // chunk <= 48 < 64
    #pragma unroll
    for (int d = 32; d > 0; d >>= 1) v += __shfl_xor(v, d);
    int i = blockIdx.x * 256 + threadIdx.x;
    if (i >= N_NODES) return;
    row_ptr[i] += v;
    if (i == 0) row_ptr[N_NODES] = EP_EDGES;
}

// atomic-free scatter: position = row_ptr[dst] + epos[e]
__global__ void scatter_k(const int* __restrict__ ei, const int* __restrict__ epos,
                          const int* __restrict__ row_ptr, int* __restrict__ col) {
    const bool i64 = probe_i64(ei);
    int e = blockIdx.x * 256 + threadIdx.x;
    if (e >= EP_EDGES) return;
    int src, dst;
    if (e < E_EDGES) {
        if (i64) { src = ei[2 * e]; dst = ei[2 * (E_EDGES + e)]; }
        else     { src = ei[e];     dst = ei[E_EDGES + e]; }
    } else { src = e - E_EDGES; dst = src; }
    col[row_ptr[dst] + epos[e]] = src;
}

// ---------------- A-fragment loader with runtime dtype branch ----------------
__device__ __forceinline__ bf16x8 loadA(const void* X, bool f32, size_t row, int off) {
    if (!f32) return *(const bf16x8*)((const ushort*)X + row * IN_DIM + off);
    const float* p = (const float*)X + row * IN_DIM + off;
    bf16x8 r;
    #pragma unroll
    for (int j = 0; j < 8; ++j) r[j] = (short)f2b(p[j]);
    return r;
}

// ---------------- fused layer-1 MFMA GEMM, split-N, 2 row-tiles/wave, raw-A ----------------
__global__ __launch_bounds__(256) void gemm3_k(const void* __restrict__ A,
                                               const ushort* __restrict__ B1,
                                               const ushort* __restrict__ B2,
                                               const ushort* __restrict__ B3,
                                               const ushort* __restrict__ bi1,
                                               const ushort* __restrict__ bi2,
                                               const ushort* __restrict__ bi3,
                                               ushort* __restrict__ o1,
                                               ushort* __restrict__ o2,
                                               ushort* __restrict__ o3,
                                               int M) {
    const bool f32 = probe_f32((const ushort*)A);
    const int wave = threadIdx.x >> 6;
    const int lane = threadIdx.x & 63;
    const int ch = blockIdx.y;
    const int row0 = blockIdx.x * 128 + wave * 32;
    if (row0 >= M) return;
    int ar0 = row0 + (lane & 15);      if (ar0 >= M) ar0 = M - 1;
    int ar1 = row0 + 16 + (lane & 15); if (ar1 >= M) ar1 = M - 1;
    const int aoff = (lane >> 4) * 8;
    bf16x8 af0[5], af1[5];
    #pragma unroll
    for (int kb = 0; kb < 5; ++kb) {
        af0[kb] = loadA(A, f32, (size_t)ar0, aoff + kb * 32);
        af1[kb] = loadA(A, f32, (size_t)ar1, aoff + kb * 32);
    }
    const bf16x8* b1 = (const bf16x8*)B1;
    const bf16x8* b2 = (const bf16x8*)B2;
    const bf16x8* b3 = (const bf16x8*)B3;
    f32x4 aL[2][8] = {}, aR[2][8] = {}, aS[2][2] = {};
    #pragma unroll
    for (int kb = 0; kb < 5; ++kb) {
        #pragma unroll
        for (int j = 0; j < 8; ++j) {
            bf16x8 b = b1[(kb * 16 + ch * 8 + j) * 64 + lane];
            aL[0][j] = __builtin_amdgcn_mfma_f32_16x16x32_bf16(af0[kb], b, aL[0][j], 0, 0, 0);
            aL[1][j] = __builtin_amdgcn_mfma_f32_16x16x32_bf16(af1[kb], b, aL[1][j], 0, 0, 0);
        }
        #pragma unroll
        for (int j = 0; j < 8; ++j) {
            bf16x8 b = b2[(kb * 16 + ch * 8 + j) * 64 + lane];
            aR[0][j] = __builtin_amdgcn_mfma_f32_16x16x32_bf16(af0[kb], b, aR[0][j], 0, 0, 0);
            aR[1][j] = __builtin_amdgcn_mfma_f32_16x16x32_bf16(af1[kb], b, aR[1][j], 0, 0, 0);
        }
        #pragma unroll
        for (int j = 0; j < 2; ++j) {
            bf16x8 b = b3[(kb * 4 + ch * 2 + j) * 64 + lane];
            aS[0][j] = __builtin_amdgcn_mfma_f32_16x16x32_bf16(af0[kb], b, aS[0][j], 0, 0, 0);
            aS[1][j] = __builtin_amdgcn_mfma_f32_16x16x32_bf16(af1[kb], b, aS[1][j], 0, 0, 0);
        }
    }
    const int cn = lane & 15, cq = lane >> 4;
    #pragma unroll
    for (int rt = 0; rt < 2; ++rt) {
        #pragma unroll
        for (int j = 0; j < 8; ++j) {
            int colc = (ch * 8 + j) * 16 + cn;
            float bbL = b2f(bi1[colc]);
            float bbR = b2f(bi2[colc]);
            #pragma unroll
            for (int r = 0; r < 4; ++r) {
                int grow = row0 + rt * 16 + cq * 4 + r;
                if (grow < M) {
                    o1[(size_t)grow * C1 + colc] = f2b(aL[rt][j][r] + bbL);
                    o2[(size_t)grow * C1 + colc] = f2b(aR[rt][j][r] + bbR);
                }
            }
        }
        #pragma unroll
        for (int j = 0; j < 2; ++j) {
            int colc = (ch * 2 + j) * 16 + cn;
            float bb = b2f(bi3[colc]);
            #pragma unroll
            for (int r = 0; r < 4; ++r) {
                int grow = row0 + rt * 16 + cq * 4 + r;
                if (grow < M)
                    o3[(size_t)grow * HID + colc] = f2b(aS[rt][j][r] + bb);
            }
        }
    }
}

// ---------------- fused layer-2 MFMA GEMM: xl2(64) + xr2(64), K=256 ----------------
__global__ __launch_bounds__(256) void gemm2_k(const ushort* __restrict__ A,
                                               const ushort* __restrict__ B1,
                                               const ushort* __restrict__ B2,
                                               const ushort* __restrict__ bi1,
                                               const ushort* __restrict__ bi2,
                                               ushort* __restrict__ o1,
                                               ushort* __restrict__ o2,
                                               int M) {
    const int wave = threadIdx.x >> 6;
    const int lane = threadIdx.x & 63;
    const int row0 = blockIdx.x * 64 + wave * 16;
    if (row0 >= M) return;
    int arow = row0 + (lane & 15);
    if (arow >= M) arow = M - 1;
    const ushort* aptr = A + (size_t)arow * C1 + (lane >> 4) * 8;
    const bf16x8* b1 = (const bf16x8*)B1;
    const bf16x8* b2 = (const bf16x8*)B2;
    f32x4 aL[4] = {}, aR[4] = {};
    #pragma unroll
    for (int kb = 0; kb < 8; ++kb) {
        bf16x8 af = *(const bf16x8*)(aptr + kb * 32);
        #pragma unroll
        for (int t = 0; t < 4; ++t)
            aL[t] = __builtin_amdgcn_mfma_f32_16x16x32_bf16(af, b1[(kb * 4 + t) * 64 + lane], aL[t], 0, 0, 0);
        #pragma unroll
        for (int t = 0; t < 4; ++t)
            aR[t] = __builtin_amdgcn_mfma_f32_16x16x32_bf16(af, b2[(kb * 4 + t) * 64 + lane], aR[t], 0, 0, 0);
    }
    const int cn = lane & 15, cq = lane >> 4;
    #pragma unroll
    for (int t = 0; t < 4; ++t) {
        float bbL = b2f(bi1[t * 16 + cn]);
        float bbR = b2f(bi2[t * 16 + cn]);
        #pragma unroll
        for (int r = 0; r < 4; ++r) {
            int grow = row0 + cq * 4 + r;
            if (grow < M) {
                o1[(size_t)grow * HID + t * 16 + cn] = f2b(aL[t][r] + bbL);
                o2[(size_t)grow * HID + t * 16 + cn] = f2b(aR[t][r] + bbR);
            }
        }
    }
}

// ---------------- conv1: 4 gather chains, maskless full trips + guarded epilogue ----------------
__global__ __launch_bounds__(256) void conv1_k(const ushort* __restrict__ xl,
                                               const ushort* __restrict__ xr,
                                               const int* __restrict__ row_ptr,
                                               const int* __restrict__ col,
                                               const ushort* __restrict__ att,
                                               const ushort* __restrict__ bias1,
                                               const ushort* __restrict__ g1,
                                               const ushort* __restrict__ b1,
                                               const ushort* __restrict__ m1,
                                               const ushort* __restrict__ v1,
                                               ushort* __restrict__ h1out) {
    const int n = blockIdx.x;
    const int h = threadIdx.x >> 6;          // wave = head
    const int lane = threadIdx.x & 63;
    const int grp = lane >> 4;               // edge slot 0..3
    const int m = lane & 15;                 // channel quad
    const uint cpi = h * 16 + m;             // uint2 index within 64-uint2 row
    const uint2* xl2v = (const uint2*)xl;
    const uint2 xru = ((const uint2*)xr)[(size_t)n * 64 + cpi];
    const float xr0 = lo16(xru.x), xr1 = hi16(xru.x);
    const float xr2 = lo16(xru.y), xr3 = hi16(xru.y);
    const uint2 atu = ((const uint2*)att)[cpi];
    const float at0 = lo16(atu.x), at1 = hi16(atu.x);
    const float at2 = lo16(atu.y), at3 = hi16(atu.y);
    const int e0 = row_ptr[n], e1 = row_ptr[n + 1];
    const int deg = e1 - e0;
    const int iend = e0 + (deg & ~15);       // end of maskless full trips
    float a0 = 0.f, a1 = 0.f, a2 = 0.f, a3 = 0.f, den = 0.f;

    auto edge4 = [&](const uint2 xu, bool masked, int jbase) {
        const float x0 = lo16(xu.x), x1 = hi16(xu.x);
        const float x2 = lo16(xu.y), x3 = hi16(xu.y);
        float t0 = x0 + xr0; t0 = fmaxf(t0, t0 * NEG_SLOPE);
        float t1 = x1 + xr1; t1 = fmaxf(t1, t1 * NEG_SLOPE);
        float t2 = x2 + xr2; t2 = fmaxf(t2, t2 * NEG_SLOPE);
        float t3 = x3 + xr3; t3 = fmaxf(t3, t3 * NEG_SLOPE);
        float p = fmaf(t0, at0, fmaf(t1, at1, fmaf(t2, at2, t3 * at3)));
        p = row16_sum(p);
        float w;
        if (masked) {
            w = __expf(fminf(p, 60.f));
            w = ((jbase + grp) < e1) ? w : 0.f;
        } else {
            w = __expf(p);   // logits bounded; no clamp in hot path
        }
        a0 = fmaf(w, x0, a0); a1 = fmaf(w, x1, a1);
        a2 = fmaf(w, x2, a2); a3 = fmaf(w, x3, a3);
        den += w;
    };

    uint s0_, s1_, s2_, s3_;
    {
        const int j0 = e0 + grp, j1 = j0 + 4, j2 = j0 + 8, j3 = j0 + 12;
        s0_ = (uint)col[j0 < e1 ? j0 : e1 - 1];
        s1_ = (uint)col[j1 < e1 ? j1 : e1 - 1];
        s2_ = (uint)col[j2 < e1 ? j2 : e1 - 1];
        s3_ = (uint)col[j3 < e1 ? j3 : e1 - 1];
    }
    for (int i = e0; i < iend; i += 16) {
        const uint2 xu0 = xl2v[(s0_ << 6) + cpi];
        const uint2 xu1 = xl2v[(s1_ << 6) + cpi];
        const uint2 xu2 = xl2v[(s2_ << 6) + cpi];
        const uint2 xu3 = xl2v[(s3_ << 6) + cpi];
        const int j0 = i + 16 + grp, j1 = j0 + 4, j2 = j0 + 8, j3 = j0 + 12;
        s0_ = (uint)col[j0 < e1 ? j0 : e1 - 1];
        s1_ = (uint)col[j1 < e1 ? j1 : e1 - 1];
        s2_ = (uint)col[j2 < e1 ? j2 : e1 - 1];
        s3_ = (uint)col[j3 < e1 ? j3 : e1 - 1];
        edge4(xu0, false, 0);
        edge4(xu1, false, 0);
        edge4(xu2, false, 0);
        edge4(xu3, false, 0);
    }
    const int rem = e1 - iend;               // 0..15
    if (rem > 0) {
        const uint2 xu0 = xl2v[(s0_ << 6) + cpi];   // all 4 issued: MLP preserved
        const uint2 xu1 = xl2v[(s1_ << 6) + cpi];
        const uint2 xu2 = xl2v[(s2_ << 6) + cpi];
        const uint2 xu3 = xl2v[(s3_ << 6) + cpi];
        edge4(xu0, true, iend);
        if (rem > 4)  edge4(xu1, true, iend + 4);
        if (rem > 8)  edge4(xu2, true, iend + 8);
        if (rem > 12) edge4(xu3, true, iend + 12);
    }
    a0 += __shfl_xor(a0, 16); a0 += __shfl_xor(a0, 32);
    a1 += __shfl_xor(a1, 16); a1 += __shfl_xor(a1, 32);
    a2 += __shfl_xor(a2, 16); a2 += __shfl_xor(a2, 32);
    a3 += __shfl_xor(a3, 16); a3 += __shfl_xor(a3, 32);
    den += __shfl_xor(den, 16); den += __shfl_xor(den, 32);
    if (lane < 16) {
        const float inv = 1.f / den;
        const uint2 biu = ((const uint2*)bias1)[cpi];
        const uint2 gu  = ((const uint2*)g1)[cpi];
        const uint2 bu  = ((const uint2*)b1)[cpi];
        const uint2 mu  = ((const uint2*)m1)[cpi];
        const uint2 vu  = ((const uint2*)v1)[cpi];
        float o0 = fmaf(a0, inv, lo16(biu.x));
        float o1 = fmaf(a1, inv, hi16(biu.x));
        float o2 = fmaf(a2, inv, lo16(biu.y));
        float o3 = fmaf(a3, inv, hi16(biu.y));
        float s0 = lo16(gu.x) * rsqrtf(lo16(vu.x) + BN_EPS);
        float s1 = hi16(gu.x) * rsqrtf(hi16(vu.x) + BN_EPS);
        float s2 = lo16(gu.y) * rsqrtf(lo16(vu.y) + BN_EPS);
        float s3 = hi16(gu.y) * rsqrtf(hi16(vu.y) + BN_EPS);
        float h0 = fmaxf((o0 - lo16(mu.x)) * s0 + lo16(bu.x), 0.f);
        float h1v = fmaxf((o1 - hi16(mu.x)) * s1 + hi16(bu.x), 0.f);
        float h2 = fmaxf((o2 - lo16(mu.y)) * s2 + lo16(bu.y), 0.f);
        float h3 = fmaxf((o3 - hi16(mu.y)) * s3 + hi16(bu.y), 0.f);
        uint2 ou;
        ou.x = (uint)f2b(h0) | ((uint)f2b(h1v) << 16);
        ou.y = (uint)f2b(h2) | ((uint)f2b(h3) << 16);
        ((uint2*)h1out)[(size_t)n * 64 + cpi] = ou;
    }
}

// ---------------- conv2 + BN2 + relu + skip + output linear ----------------
__global__ __launch_bounds__(256) void conv2_k(const ushort* __restrict__ xl,
                                               const ushort* __restrict__ xr,
                                               const ushort* __restrict__ xskip,
                                               const int* __restrict__ row_ptr,
                                               const int* __restrict__ col,
                                               const ushort* __restrict__ att2,
                                               const ushort* __restrict__ bias2,
                                               const ushort* __restrict__ g2,
                                               const ushort* __restrict__ bb2,
                                               const ushort* __restrict__ m2,
                                               const ushort* __restrict__ v2,
                                               const ushort* __restrict__ Wo,
                                               const ushort* __restrict__ bo,
                                               void* __restrict__ out,
                                               const ushort* __restrict__ xraw) {
    const bool f32out = probe_f32(xraw);
    const int n = blockIdx.x * 4 + (threadIdx.x >> 6);
    if (n >= N_NODES) return;
    const int lane = threadIdx.x & 63;
    const int grp = lane >> 4;
    const uint m = lane & 15;                // uint2 index within 16-uint2 row
    const uint2* xl2v = (const uint2*)xl;
    const uint2 xru = ((const uint2*)xr)[(size_t)n * 16 + m];
    const float xr0 = lo16(xru.x), xr1 = hi16(xru.x);
    const float xr2 = lo16(xru.y), xr3 = hi16(xru.y);
    const uint2 atu = ((const uint2*)att2)[m];
    const float at0 = lo16(atu.x), at1 = hi16(atu.x);
    const float at2 = lo16(atu.y), at3 = hi16(atu.y);
    const int e0 = row_ptr[n], e1 = row_ptr[n + 1];
    const int deg = e1 - e0;
    const int iend = e0 + (deg & ~15);
    float a0 = 0.f, a1 = 0.f, a2 = 0.f, a3 = 0.f, den = 0.f;

    auto edge4 = [&](const uint2 xu, bool masked, int jbase) {
        const float x0 = lo16(xu.x), x1 = hi16(xu.x);
        const float x2 = lo16(xu.y), x3 = hi16(xu.y);
        float t0 = x0 + xr0; t0 = fmaxf(t0, t0 * NEG_SLOPE);
        float t1 = x1 + xr1; t1 = fmaxf(t1, t1 * NEG_SLOPE);
        float t2 = x2 + xr2; t2 = fmaxf(t2, t2 * NEG_SLOPE);
        float t3 = x3 + xr3; t3 = fmaxf(t3, t3 * NEG_SLOPE);
        float p = fmaf(t0, at0, fmaf(t1, at1, fmaf(t2, at2, t3 * at3)));
        p = row16_sum(p);
        float w;
        if (masked) {
            w = __expf(fminf(p, 60.f));
            w = ((jbase + grp) < e1) ? w : 0.f;
        } else {
            w = __expf(p);
        }
        a0 = fmaf(w, x0, a0); a1 = fmaf(w, x1, a1);
        a2 = fmaf(w, x2, a2); a3 = fmaf(w, x3, a3);
        den += w;
    };

    uint s0_, s1_, s2_, s3_;
    {
        const int j0 = e0 + grp, j1 = j0 + 4, j2 = j0 + 8, j3 = j0 + 12;
        s0_ = (uint)col[j0 < e1 ? j0 : e1 - 1];
        s1_ = (uint)col[j1 < e1 ? j1 : e1 - 1];
        s2_ = (uint)col[j2 < e1 ? j2 : e1 - 1];
        s3_ = (uint)col[j3 < e1 ? j3 : e1 - 1];
    }
    for (int i = e0; i < iend; i += 16) {
        const uint2 xu0 = xl2v[(s0_ << 4) + m];
        const uint2 xu1 = xl2v[(s1_ << 4) + m];
        const uint2 xu2 = xl2v[(s2_ << 4) + m];
        const uint2 xu3 = xl2v[(s3_ << 4) + m];
        const int j0 = i + 16 + grp, j1 = j0 + 4, j2 = j0 + 8, j3 = j0 + 12;
        s0_ = (uint)col[j0 < e1 ? j0 : e1 - 1];
        s1_ = (uint)col[j1 < e1 ? j1 : e1 - 1];
        s2_ = (uint)col[j2 < e1 ? j2 : e1 - 1];
        s3_ = (uint)col[j3 < e1 ? j3 : e1 - 1];
        edge4(xu0, false, 0);
        edge4(xu1, false, 0);
        edge4(xu2, false, 0);
        edge4(xu3, false, 0);
    }
    const int rem = e1 - iend;
    if (rem > 0) {
        const uint2 xu0 = xl2v[(s0_ << 4) + m];
        const uint2 xu1 = xl2v[(s1_ << 4) + m];
        const uint2 xu2 = xl2v[(s2_ << 4) + m];
        const uint2 xu3 = xl2v[(s3_ << 4) + m];
        edge4(xu0, true, iend);
        if (rem > 4)  edge4(xu1, true, iend + 4);
        if (rem > 8)  edge4(xu2, true, iend + 8);
        if (rem > 12) edge4(xu3, true, iend + 12);
    }
    a0 += __shfl_xor(a0, 16); a0 += __shfl_xor(a0, 32);
    a1 += __shfl_xor(a1, 16); a1 += __shfl_xor(a1, 32);
    a2 += __shfl_xor(a2, 16); a2 += __shfl_xor(a2, 32);
    a3 += __shfl_xor(a3, 16); a3 += __shfl_xor(a3, 32);
    den += __shfl_xor(den, 16); den += __shfl_xor(den, 32);
    if (lane < 16) {
        const float inv = 1.f / den;
        const uint2 biu = ((const uint2*)bias2)[m];
        const uint2 gu  = ((const uint2*)g2)[m];
        const uint2 bu  = ((const uint2*)bb2)[m];
        const uint2 mu  = ((const uint2*)m2)[m];
        const uint2 vu  = ((const uint2*)v2)[m];
        const uint2 sku = ((const uint2*)xskip)[(size_t)n * 16 + m];
        const uint2 wou = ((const uint2*)Wo)[m];
        float o0 = fmaf(a0, inv, lo16(biu.x));
        float o1 = fmaf(a1, inv, hi16(biu.x));
        float o2 = fmaf(a2, inv, lo16(biu.y));
        float o3 = fmaf(a3, inv, hi16(biu.y));
        float s0 = lo16(gu.x) * rsqrtf(lo16(vu.x) + BN_EPS);
        float s1 = hi16(gu.x) * rsqrtf(hi16(vu.x) + BN_EPS);
        float s2 = lo16(gu.y) * rsqrtf(lo16(vu.y) + BN_EPS);
        float s3 = hi16(gu.y) * rsqrtf(hi16(vu.y) + BN_EPS);
        float h0 = fmaxf((o0 - lo16(mu.x)) * s0 + lo16(bu.x), 0.f) + lo16(sku.x);
        float h1v = fmaxf((o1 - hi16(mu.x)) * s1 + hi16(bu.x), 0.f) + hi16(sku.x);
        float h2 = fmaxf((o2 - lo16(mu.y)) * s2 + lo16(bu.y), 0.f) + lo16(sku.y);
        float h3 = fmaxf((o3 - hi16(mu.y)) * s3 + hi16(bu.y), 0.f) + hi16(sku.y);
        float d = fmaf(h0, lo16(wou.x), fmaf(h1v, hi16(wou.x),
                  fmaf(h2, lo16(wou.y), h3 * hi16(wou.y))));
        d = row16_sum(d);
        if (m == 0) {
            float r = d + b2f(bo[0]);
            if (f32out) ((float*)out)[n] = r;
            else        ((ushort*)out)[n] = f2b(r);
        }
    }
}

extern "C" void kernel_launch(void* const* d_in, const int* in_sizes, int n_in,
                              void* d_out, int out_size, void* d_ws, size_t ws_size,
                              hipStream_t stream) {
    char* ws = (char*)d_ws;
    size_t off = 0;
    auto alloc = [&](size_t bytes) -> void* {
        void* p = ws + off;
        off += (bytes + 255) & ~(size_t)255;
        return p;
    };
    ushort* params  = (ushort*)alloc((size_t)127617 * 2);
    int*    row_ptr = (int*)alloc((size_t)(N_NODES + 1) * 4);
    int*    deg     = (int*)alloc((size_t)N_NODES * 4);
    int*    epos    = (int*)alloc((size_t)EP_EDGES * 4);
    int*    colbuf  = (int*)alloc((size_t)EP_EDGES * 4);
    int*    bsum    = (int*)alloc(64 * 4);
    ushort* xl1     = (ushort*)alloc((size_t)N_NODES * C1 * 2);
    ushort* xr1     = (ushort*)alloc((size_t)N_NODES * C1 * 2);
    ushort* xskip   = (ushort*)alloc((size_t)N_NODES * HID * 2);
    ushort* h1      = (ushort*)alloc((size_t)N_NODES * C1 * 2);
    ushort* xl2     = (ushort*)alloc((size_t)N_NODES * HID * 2);
    ushort* xr2     = (ushort*)alloc((size_t)N_NODES * HID * 2);
    ushort* swzWl1  = (ushort*)alloc((size_t)IN_DIM * C1 * 2);
    ushort* swzWr1  = (ushort*)alloc((size_t)IN_DIM * C1 * 2);
    ushort* swzWs   = (ushort*)alloc((size_t)IN_DIM * HID * 2);
    ushort* swzWl2  = (ushort*)alloc((size_t)C1 * HID * 2);
    ushort* swzWr2  = (ushort*)alloc((size_t)C1 * HID * 2);

    ushort* bl1c   = params + 40960;
    ushort* br1c   = params + 82176;
    ushort* att1c  = params + 82432;
    ushort* bias1c = params + 82688;
    ushort* g1c    = params + 82944;
    ushort* b1c    = params + 83200;
    ushort* m1c    = params + 83456;
    ushort* v1c    = params + 83712;
    ushort* bl2c   = params + 100352;
    ushort* br2c   = params + 116800;
    ushort* att2c  = params + 116864;
    ushort* bias2c = params + 116928;
    ushort* g2c    = params + 116992;
    ushort* b2c    = params + 117056;
    ushort* m2c    = params + 117120;
    ushort* v2c    = params + 117184;
    ushort* bsc    = params + 127488;
    ushort* Woc    = params + 127552;
    ushort* boc    = params + 127616;

    const int* ei_raw = (const int*)d_in[1];

    // ---- deg = 0 (needed by fused hist) ----
    hipMemsetAsync(deg, 0, (size_t)N_NODES * 4, stream);

    // ---- fused front-end: swizzle+params | hist(+epos) ----
    SW2 sw;
    sw.W[0] = d_in[2];  sw.D[0] = swzWl1; sw.NT[0] = 16; sw.base[0] = 0;      // Wl1
    sw.W[1] = d_in[4];  sw.D[1] = swzWr1; sw.NT[1] = 16; sw.base[1] = 5120;   // Wr1
    sw.W[2] = d_in[22]; sw.D[2] = swzWs;  sw.NT[2] = 4;  sw.base[2] = 10240;  // Ws
    sw.W[3] = d_in[12]; sw.D[3] = swzWl2; sw.NT[3] = 4;  sw.base[3] = 11520;  // Wl2
    sw.W[4] = d_in[14]; sw.D[4] = swzWr2; sw.NT[4] = 4;  sw.base[4] = 13568;  // Wr2
    const int spidx[19] = {3,5,6,7,8,9,10,11, 13,15,16,17,18,19,20,21, 23,24, 25};
    for (int i = 0; i < 19; ++i) sw.sp[i] = d_in[spidx[i]];
    sw.xraw = d_in[0];
    front_k<<<NB_SWZ + NB_HIST, 256, 0, stream>>>(ei_raw, deg, epos, sw, params);

    const int NB_N = (N_NODES + 255) / 256;        // 196
    const int NB_E = (EP_EDGES + 255) / 256;       // 3321
    const int NB_S = (N_NODES + 1023) / 1024;      // 49

    // ---- CSR scan + atomic-free scatter ----
    scan1_k<<<NB_S, 1024, 0, stream>>>(deg, row_ptr, bsum);
    scan3_k<<<NB_N, 256, 0, stream>>>(row_ptr, bsum);
    scatter_k<<<NB_E, 256, 0, stream>>>(ei_raw, epos, row_ptr, colbuf);

    // ---- layer-1 linear transforms (+ skip), fused MFMA, raw-A ----
    gemm3_k<<<dim3((N_NODES + 127) / 128, 2), 256, 0, stream>>>(
        d_in[0], swzWl1, swzWr1, swzWs, bl1c, br1c, bsc, xl1, xr1, xskip, N_NODES);

    // ---- conv1 edge aggregation + BN1 + relu ----
    conv1_k<<<N_NODES, 256, 0, stream>>>(xl1, xr1, row_ptr, colbuf, att1c, bias1c,
                                         g1c, b1c, m1c, v1c, h1);

    // ---- layer-2 linear transforms, fused MFMA ----
    gemm2_k<<<(N_NODES + 63) / 64, 256, 0, stream>>>(h1, swzWl2, swzWr2, bl2c, br2c,
                                                     xl2, xr2, N_NODES);

    // ---- conv2 + BN2 + relu + skip + output linear ----
    conv2_k<<<(N_NODES + 3) / 4, 256, 0, stream>>>(xl2, xr2, xskip, row_ptr, colbuf,
                                                   att2c, bias2c, g2c, b2c, m2c, v2c,
                                                   Woc, boc, d_out, (const ushort*)d_in[0]);
}

// Round 14
// 396.326 us; speedup vs baseline: 1.1371x; 1.0030x over previous
//
#include <hip/hip_runtime.h>
#include <hip/hip_bf16.h>

#define N_NODES 50000
#define E_EDGES 800000
#define EP_EDGES 850000   // E + N self loops
#define IN_DIM 160
#define HEADS 4
#define HID 64
#define C1 256            // HEADS*HID
#define NEG_SLOPE 0.2f
#define BN_EPS 1e-5f

typedef __attribute__((ext_vector_type(8))) short bf16x8;
typedef __attribute__((ext_vector_type(4))) float f32x4;

__device__ __forceinline__ float b2f(ushort u) {
    return __uint_as_float(((unsigned)u) << 16);
}
__device__ __forceinline__ ushort f2b(float f) {
    __hip_bfloat16 h = __float2bfloat16(f);
    return *reinterpret_cast<ushort*>(&h);
}
__device__ __forceinline__ float lo16(uint u) { return __uint_as_float(u << 16); }
__device__ __forceinline__ float hi16(uint u) { return __uint_as_float(u & 0xffff0000u); }

// ---- in-kernel dtype probes (wave-wide, 1 read + ballot) ----
__device__ __forceinline__ bool probe_f32(const ushort* xraw) {
    int lane = threadIdx.x & 63;
    float a = fabsf(b2f(xraw[2 * lane]));
    unsigned long long m = __ballot(a > 1e-6f && a < 1e6f);
    return __popcll(m) < 48;
}
__device__ __forceinline__ bool probe_i64(const int* eraw) {
    int lane = threadIdx.x & 63;
    unsigned long long m = __ballot(eraw[2 * lane + 1] != 0);
    return __popcll(m) < 8;
}

// DPP-based add of a permuted copy: pure VALU pipe
template<int CTRL>
__device__ __forceinline__ float dpp_add(float p) {
    int t = __builtin_amdgcn_update_dpp(0, __float_as_int(p), CTRL, 0xf, 0xf, true);
    return p + __int_as_float(t);
}
// sum over each 16-lane row; all 16 lanes get the row total
__device__ __forceinline__ float row16_sum(float p) {
    p = dpp_add<0xB1>(p);    // quad_perm xor1
    p = dpp_add<0x4E>(p);    // quad_perm xor2
    p = dpp_add<0x124>(p);   // row_ror:4
    p = dpp_add<0x128>(p);   // row_ror:8
    return p;
}

// ---------------- fused front-end: weight swizzle + params | hist(+epos) ----------------
// deg must be zeroed (hipMemsetAsync) before this kernel.
#define NB_SWZ 62
#define NB_HIST 3321

struct SW2 {
    const void* W[5];    // raw Wl1, Wr1, Ws, Wl2, Wr2
    ushort* D[5];
    int NT[5];
    int base[5];
    const void* sp[19];  // raw small tensors
    const void* xraw;
};

__global__ void front_k(const int* __restrict__ ei, int* __restrict__ deg,
                        int* __restrict__ epos, SW2 s, ushort* __restrict__ params) {
    const int b = blockIdx.x;
    if (b < NB_SWZ) {
        const bool f32 = probe_f32((const ushort*)s.xraw);
        if (b < 61) {
            int idx = b * 256 + threadIdx.x;     // < 15616
            int seg = 0;
            #pragma unroll
            for (int k = 1; k < 5; ++k) seg += (idx >= s.base[k]) ? 1 : 0;
            int li = idx - s.base[seg];
            int NT = s.NT[seg];
            int N = NT << 4;
            int lane = li & 63;
            int ft = li >> 6;
            int kb = ft / NT, t = ft - kb * NT;
            int q = lane >> 4, m = lane & 15;
            const float* pf = (const float*)s.W[seg];
            const ushort* pu = (const ushort*)s.W[seg];
            ushort* d = s.D[seg] + (size_t)li * 8;
            #pragma unroll
            for (int j = 0; j < 8; ++j) {
                size_t src = (size_t)(kb * 32 + q * 8 + j) * N + t * 16 + m;
                d[j] = f32 ? f2b(pf[src]) : pu[src];
            }
        } else {
            const int SZ[19] = {256,256,256,256,256,256,256,256,
                                64,64,64,64,64,64,64,64,64,64, 1};
            const int OF[19] = {40960,82176,82432,82688,82944,83200,83456,83712,
                                100352,116800,116864,116928,116992,117056,117120,117184,
                                127488,127552, 127616};
            for (int e = threadIdx.x; e < 2689; e += 256) {
                int rem = e, t = 0;
                while (rem >= SZ[t]) { rem -= SZ[t]; ++t; }
                const float* pf = (const float*)s.sp[t];
                const ushort* pu = (const ushort*)s.sp[t];
                params[OF[t] + rem] = f32 ? f2b(pf[rem]) : pu[rem];
            }
        }
    } else {
        const bool i64 = probe_i64(ei);
        int e = (b - NB_SWZ) * 256 + threadIdx.x;
        if (e >= EP_EDGES) return;
        int dst;
        if (e < E_EDGES) {
            int idx = E_EDGES + e;
            dst = i64 ? ei[2 * idx] : ei[idx];
        } else dst = e - E_EDGES;
        epos[e] = atomicAdd(&deg[dst], 1);   // slot within node; reused by scatter
    }
}

// ---------------- block scan via wave shfl + LDS (2 barriers) ----------------
__global__ __launch_bounds__(1024) void scan1_k(const int* __restrict__ deg,
                                                int* __restrict__ exc,
                                                int* __restrict__ bsum) {
    __shared__ int wsum[16];
    const int t = threadIdx.x;
    const int lane = t & 63, w = t >> 6;
    int i = blockIdx.x * 1024 + t;
    int v = (i < N_NODES) ? deg[i] : 0;
    int sIncl = v;
    #pragma unroll
    for (int d = 1; d < 64; d <<= 1) {
        int u = __shfl_up(sIncl, d);
        if (lane >= d) sIncl += u;
    }
    if (lane == 63) wsum[w] = sIncl;
    __syncthreads();
    if (w == 0) {
        int p = (lane < 16) ? wsum[lane] : 0;
        #pragma unroll
        for (int d = 1; d < 16; d <<= 1) {
            int u = __shfl_up(p, d);
            if (lane >= d) p += u;
        }
        if (lane < 16) wsum[lane] = p;
    }
    __syncthreads();
    int base = (w > 0) ? wsum[w - 1] : 0;
    int incl = base + sIncl;
    if (i < N_NODES) exc[i] = incl - v;
    if (t == 1023) bsum[blockIdx.x] = incl;
}

// 1-wave exclusive scan of the 49 chunk sums; also closes exc[N]
__global__ void scan2_k(const int* __restrict__ bsum, int* __restrict__ cp,
                        int* __restrict__ exc) {
    int lane = threadIdx.x;   // 64
    int v = (lane < 49) ? bsum[lane] : 0;
    int orig = v;
    #pragma unroll
    for (int d = 1; d < 64; d <<= 1) {
        int u = __shfl_up(v, d);
        if (lane >= d) v += u;
    }
    if (lane < 49) cp[lane] = v - orig;               // exclusive prefix
    if (lane == 48) exc[N_NODES] = EP_EDGES - (v - orig);
}

// ---------------- A-fragment loader with runtime dtype branch ----------------
__device__ __forceinline__ bf16x8 loadA(const void* X, bool f32, size_t row, int off) {
    if (!f32) return *(const bf16x8*)((const ushort*)X + row * IN_DIM + off);
    const float* p = (const float*)X + row * IN_DIM + off;
    bf16x8 r;
    #pragma unroll
    for (int j = 0; j < 8; ++j) r[j] = (short)f2b(p[j]);
    return r;
}

// ---------------- fused: gemm3 (blocks 0..781) | scatter (blocks 782..4102) ----------------
#define NB_G3 782   // 391 row-blocks x 2 col-halves

__global__ __launch_bounds__(256) void scatgemm_k(const void* __restrict__ A,
                                                  const ushort* __restrict__ B1,
                                                  const ushort* __restrict__ B2,
                                                  const ushort* __restrict__ B3,
                                                  const ushort* __restrict__ bi1,
                                                  const ushort* __restrict__ bi2,
                                                  const ushort* __restrict__ bi3,
                                                  ushort* __restrict__ o1,
                                                  ushort* __restrict__ o2,
                                                  ushort* __restrict__ o3,
                                                  int M,
                                                  const int* __restrict__ ei,
                                                  const int* __restrict__ epos,
                                                  const int* __restrict__ exc,
                                                  const int* __restrict__ cp,
                                                  int* __restrict__ col) {
    if (blockIdx.x >= NB_G3) {
        // ---- scatter (atomic-free) ----
        const bool i64 = probe_i64(ei);
        int e = (blockIdx.x - NB_G3) * 256 + threadIdx.x;
        if (e >= EP_EDGES) return;
        int src, dst;
        if (e < E_EDGES) {
            if (i64) { src = ei[2 * e]; dst = ei[2 * (E_EDGES + e)]; }
            else     { src = ei[e];     dst = ei[E_EDGES + e]; }
        } else { src = e - E_EDGES; dst = src; }
        col[exc[dst] + cp[dst >> 10] + epos[e]] = src;
        return;
    }
    // ---- gemm3: split-N, 2 row-tiles/wave, raw-A ----
    const bool f32 = probe_f32((const ushort*)A);
    const int wave = threadIdx.x >> 6;
    const int lane = threadIdx.x & 63;
    const int ch = blockIdx.x & 1;
    const int row0 = (blockIdx.x >> 1) * 128 + wave * 32;
    if (row0 >= M) return;
    int ar0 = row0 + (lane & 15);      if (ar0 >= M) ar0 = M - 1;
    int ar1 = row0 + 16 + (lane & 15); if (ar1 >= M) ar1 = M - 1;
    const int aoff = (lane >> 4) * 8;
    bf16x8 af0[5], af1[5];
    #pragma unroll
    for (int kb = 0; kb < 5; ++kb) {
        af0[kb] = loadA(A, f32, (size_t)ar0, aoff + kb * 32);
        af1[kb] = loadA(A, f32, (size_t)ar1, aoff + kb * 32);
    }
    const bf16x8* b1 = (const bf16x8*)B1;
    const bf16x8* b2 = (const bf16x8*)B2;
    const bf16x8* b3 = (const bf16x8*)B3;
    f32x4 aL[2][8] = {}, aR[2][8] = {}, aS[2][2] = {};
    #pragma unroll
    for (int kb = 0; kb < 5; ++kb) {
        #pragma unroll
        for (int j = 0; j < 8; ++j) {
            bf16x8 b = b1[(kb * 16 + ch * 8 + j) * 64 + lane];
            aL[0][j] = __builtin_amdgcn_mfma_f32_16x16x32_bf16(af0[kb], b, aL[0][j], 0, 0, 0);
            aL[1][j] = __builtin_amdgcn_mfma_f32_16x16x32_bf16(af1[kb], b, aL[1][j], 0, 0, 0);
        }
        #pragma unroll
        for (int j = 0; j < 8; ++j) {
            bf16x8 b = b2[(kb * 16 + ch * 8 + j) * 64 + lane];
            aR[0][j] = __builtin_amdgcn_mfma_f32_16x16x32_bf16(af0[kb], b, aR[0][j], 0, 0, 0);
            aR[1][j] = __builtin_amdgcn_mfma_f32_16x16x32_bf16(af1[kb], b, aR[1][j], 0, 0, 0);
        }
        #pragma unroll
        for (int j = 0; j < 2; ++j) {
            bf16x8 b = b3[(kb * 4 + ch * 2 + j) * 64 + lane];
            aS[0][j] = __builtin_amdgcn_mfma_f32_16x16x32_bf16(af0[kb], b, aS[0][j], 0, 0, 0);
            aS[1][j] = __builtin_amdgcn_mfma_f32_16x16x32_bf16(af1[kb], b, aS[1][j], 0, 0, 0);
        }
    }
    const int cn = lane & 15, cq = lane >> 4;
    #pragma unroll
    for (int rt = 0; rt < 2; ++rt) {
        #pragma unroll
        for (int j = 0; j < 8; ++j) {
            int colc = (ch * 8 + j) * 16 + cn;
            float bbL = b2f(bi1[colc]);
            float bbR = b2f(bi2[colc]);
            #pragma unroll
            for (int r = 0; r < 4; ++r) {
                int grow = row0 + rt * 16 + cq * 4 + r;
                if (grow < M) {
                    o1[(size_t)grow * C1 + colc] = f2b(aL[rt][j][r] + bbL);
                    o2[(size_t)grow * C1 + colc] = f2b(aR[rt][j][r] + bbR);
                }
            }
        }
        #pragma unroll
        for (int j = 0; j < 2; ++j) {
            int colc = (ch * 2 + j) * 16 + cn;
            float bb = b2f(bi3[colc]);
            #pragma unroll
            for (int r = 0; r < 4; ++r) {
                int grow = row0 + rt * 16 + cq * 4 + r;
                if (grow < M)
                    o3[(size_t)grow * HID + colc] = f2b(aS[rt][j][r] + bb);
            }
        }
    }
}

// ---------------- fused layer-2 MFMA GEMM: xl2(64) + xr2(64), K=256 ----------------
__global__ __launch_bounds__(256) void gemm2_k(const ushort* __restrict__ A,
                                               const ushort* __restrict__ B1,
                                               const ushort* __restrict__ B2,
                                               const ushort* __restrict__ bi1,
                                               const ushort* __restrict__ bi2,
                                               ushort* __restrict__ o1,
                                               ushort* __restrict__ o2,
                                               int M) {
    const int wave = threadIdx.x >> 6;
    const int lane = threadIdx.x & 63;
    const int row0 = blockIdx.x * 64 + wave * 16;
    if (row0 >= M) return;
    int arow = row0 + (lane & 15);
    if (arow >= M) arow = M - 1;
    const ushort* aptr = A + (size_t)arow * C1 + (lane >> 4) * 8;
    const bf16x8* b1 = (const bf16x8*)B1;
    const bf16x8* b2 = (const bf16x8*)B2;
    f32x4 aL[4] = {}, aR[4] = {};
    #pragma unroll
    for (int kb = 0; kb < 8; ++kb) {
        bf16x8 af = *(const bf16x8*)(aptr + kb * 32);
        #pragma unroll
        for (int t = 0; t < 4; ++t)
            aL[t] = __builtin_amdgcn_mfma_f32_16x16x32_bf16(af, b1[(kb * 4 + t) * 64 + lane], aL[t], 0, 0, 0);
        #pragma unroll
        for (int t = 0; t < 4; ++t)
            aR[t] = __builtin_amdgcn_mfma_f32_16x16x32_bf16(af, b2[(kb * 4 + t) * 64 + lane], aR[t], 0, 0, 0);
    }
    const int cn = lane & 15, cq = lane >> 4;
    #pragma unroll
    for (int t = 0; t < 4; ++t) {
        float bbL = b2f(bi1[t * 16 + cn]);
        float bbR = b2f(bi2[t * 16 + cn]);
        #pragma unroll
        for (int r = 0; r < 4; ++r) {
            int grow = row0 + cq * 4 + r;
            if (grow < M) {
                o1[(size_t)grow * HID + t * 16 + cn] = f2b(aL[t][r] + bbL);
                o2[(size_t)grow * HID + t * 16 + cn] = f2b(aR[t][r] + bbR);
            }
        }
    }
}

// ---------------- conv1: 4 gather chains, maskless full trips + guarded epilogue ----------------
__global__ __launch_bounds__(256) void conv1_k(const ushort* __restrict__ xl,
                                               const ushort* __restrict__ xr,
                                               const int* __restrict__ exc,
                                               const int* __restrict__ cp,
                                               const int* __restrict__ col,
                                               const ushort* __restrict__ att,
                                               const ushort* __restrict__ bias1,
                                               const ushort* __restrict__ g1,
                                               const ushort* __restrict__ b1,
                                               const ushort* __restrict__ m1,
                                               const ushort* __restrict__ v1,
                                               ushort* __restrict__ h1out) {
    const int n = blockIdx.x;
    const int h = threadIdx.x >> 6;          // wave = head
    const int lane = threadIdx.x & 63;
    const int grp = lane >> 4;               // edge slot 0..3
    const int m = lane & 15;                 // channel quad
    const uint cpi = h * 16 + m;             // uint2 index within 64-uint2 row
    const uint2* xl2v = (const uint2*)xl;
    const uint2 xru = ((const uint2*)xr)[(size_t)n * 64 + cpi];
    const float xr0 = lo16(xru.x), xr1 = hi16(xru.x);
    const float xr2 = lo16(xru.y), xr3 = hi16(xru.y);
    const uint2 atu = ((const uint2*)att)[cpi];
    const float at0 = lo16(atu.x), at1 = hi16(atu.x);
    const float at2 = lo16(atu.y), at3 = hi16(atu.y);
    const int e0 = exc[n] + cp[n >> 10];
    const int e1 = exc[n + 1] + cp[(n + 1) >> 10];
    const int deg = e1 - e0;
    const int iend = e0 + (deg & ~15);       // end of maskless full trips
    float a0 = 0.f, a1 = 0.f, a2 = 0.f, a3 = 0.f, den = 0.f;

    auto edge4 = [&](const uint2 xu, bool masked, int jbase) {
        const float x0 = lo16(xu.x), x1 = hi16(xu.x);
        const float x2 = lo16(xu.y), x3 = hi16(xu.y);
        float t0 = x0 + xr0; t0 = fmaxf(t0, t0 * NEG_SLOPE);
        float t1 = x1 + xr1; t1 = fmaxf(t1, t1 * NEG_SLOPE);
        float t2 = x2 + xr2; t2 = fmaxf(t2, t2 * NEG_SLOPE);
        float t3 = x3 + xr3; t3 = fmaxf(t3, t3 * NEG_SLOPE);
        float p = fmaf(t0, at0, fmaf(t1, at1, fmaf(t2, at2, t3 * at3)));
        p = row16_sum(p);
        float w;
        if (masked) {
            w = __expf(fminf(p, 60.f));
            w = ((jbase + grp) < e1) ? w : 0.f;
        } else {
            w = __expf(p);   // logits bounded; no clamp in hot path
        }
        a0 = fmaf(w, x0, a0); a1 = fmaf(w, x1, a1);
        a2 = fmaf(w, x2, a2); a3 = fmaf(w, x3, a3);
        den += w;
    };

    uint s0_, s1_, s2_, s3_;
    {
        const int j0 = e0 + grp, j1 = j0 + 4, j2 = j0 + 8, j3 = j0 + 12;
        s0_ = (uint)col[j0 < e1 ? j0 : e1 - 1];
        s1_ = (uint)col[j1 < e1 ? j1 : e1 - 1];
        s2_ = (uint)col[j2 < e1 ? j2 : e1 - 1];
        s3_ = (uint)col[j3 < e1 ? j3 : e1 - 1];
    }
    for (int i = e0; i < iend; i += 16) {
        const uint2 xu0 = xl2v[(s0_ << 6) + cpi];
        const uint2 xu1 = xl2v[(s1_ << 6) + cpi];
        const uint2 xu2 = xl2v[(s2_ << 6) + cpi];
        const uint2 xu3 = xl2v[(s3_ << 6) + cpi];
        const int j0 = i + 16 + grp, j1 = j0 + 4, j2 = j0 + 8, j3 = j0 + 12;
        s0_ = (uint)col[j0 < e1 ? j0 : e1 - 1];
        s1_ = (uint)col[j1 < e1 ? j1 : e1 - 1];
        s2_ = (uint)col[j2 < e1 ? j2 : e1 - 1];
        s3_ = (uint)col[j3 < e1 ? j3 : e1 - 1];
        edge4(xu0, false, 0);
        edge4(xu1, false, 0);
        edge4(xu2, false, 0);
        edge4(xu3, false, 0);
    }
    const int rem = e1 - iend;               // 0..15
    if (rem > 0) {
        const uint2 xu0 = xl2v[(s0_ << 6) + cpi];   // all 4 issued: MLP preserved
        const uint2 xu1 = xl2v[(s1_ << 6) + cpi];
        const uint2 xu2 = xl2v[(s2_ << 6) + cpi];
        const uint2 xu3 = xl2v[(s3_ << 6) + cpi];
        edge4(xu0, true, iend);
        if (rem > 4)  edge4(xu1, true, iend + 4);
        if (rem > 8)  edge4(xu2, true, iend + 8);
        if (rem > 12) edge4(xu3, true, iend + 12);
    }
    a0 += __shfl_xor(a0, 16); a0 += __shfl_xor(a0, 32);
    a1 += __shfl_xor(a1, 16); a1 += __shfl_xor(a1, 32);
    a2 += __shfl_xor(a2, 16); a2 += __shfl_xor(a2, 32);
    a3 += __shfl_xor(a3, 16); a3 += __shfl_xor(a3, 32);
    den += __shfl_xor(den, 16); den += __shfl_xor(den, 32);
    if (lane < 16) {
        const float inv = 1.f / den;
        const uint2 biu = ((const uint2*)bias1)[cpi];
        const uint2 gu  = ((const uint2*)g1)[cpi];
        const uint2 bu  = ((const uint2*)b1)[cpi];
        const uint2 mu  = ((const uint2*)m1)[cpi];
        const uint2 vu  = ((const uint2*)v1)[cpi];
        float o0 = fmaf(a0, inv, lo16(biu.x));
        float o1 = fmaf(a1, inv, hi16(biu.x));
        float o2 = fmaf(a2, inv, lo16(biu.y));
        float o3 = fmaf(a3, inv, hi16(biu.y));
        float s0 = lo16(gu.x) * rsqrtf(lo16(vu.x) + BN_EPS);
        float s1 = hi16(gu.x) * rsqrtf(hi16(vu.x) + BN_EPS);
        float s2 = lo16(gu.y) * rsqrtf(lo16(vu.y) + BN_EPS);
        float s3 = hi16(gu.y) * rsqrtf(hi16(vu.y) + BN_EPS);
        float h0 = fmaxf((o0 - lo16(mu.x)) * s0 + lo16(bu.x), 0.f);
        float h1v = fmaxf((o1 - hi16(mu.x)) * s1 + hi16(bu.x), 0.f);
        float h2 = fmaxf((o2 - lo16(mu.y)) * s2 + lo16(bu.y), 0.f);
        float h3 = fmaxf((o3 - hi16(mu.y)) * s3 + hi16(bu.y), 0.f);
        uint2 ou;
        ou.x = (uint)f2b(h0) | ((uint)f2b(h1v) << 16);
        ou.y = (uint)f2b(h2) | ((uint)f2b(h3) << 16);
        ((uint2*)h1out)[(size_t)n * 64 + cpi] = ou;
    }
}

// ---------------- conv2 + BN2 + relu + skip + output linear ----------------
__global__ __launch_bounds__(256) void conv2_k(const ushort* __restrict__ xl,
                                               const ushort* __restrict__ xr,
                                               const ushort* __restrict__ xskip,
                                               const int* __restrict__ exc,
                                               const int* __restrict__ cp,
                                               const int* __restrict__ col,
                                               const ushort* __restrict__ att2,
                                               const ushort* __restrict__ bias2,
                                               const ushort* __restrict__ g2,
                                               const ushort* __restrict__ bb2,
                                               const ushort* __restrict__ m2,
                                               const ushort* __restrict__ v2,
                                               const ushort* __restrict__ Wo,
                                               const ushort* __restrict__ bo,
                                               void* __restrict__ out,
                                               const ushort* __restrict__ xraw) {
    const bool f32out = probe_f32(xraw);
    const int n = blockIdx.x * 4 + (threadIdx.x >> 6);
    if (n >= N_NODES) return;
    const int lane = threadIdx.x & 63;
    const int grp = lane >> 4;
    const uint m = lane & 15;                // uint2 index within 16-uint2 row
    const uint2* xl2v = (const uint2*)xl;
    const uint2 xru = ((const uint2*)xr)[(size_t)n * 16 + m];
    const float xr0 = lo16(xru.x), xr1 = hi16(xru.x);
    const float xr2 = lo16(xru.y), xr3 = hi16(xru.y);
    const uint2 atu = ((const uint2*)att2)[m];
    const float at0 = lo16(atu.x), at1 = hi16(atu.x);
    const float at2 = lo16(atu.y), at3 = hi16(atu.y);
    const int e0 = exc[n] + cp[n >> 10];
    const int e1 = exc[n + 1] + cp[(n + 1) >> 10];
    const int deg = e1 - e0;
    const int iend = e0 + (deg & ~15);
    float a0 = 0.f, a1 = 0.f, a2 = 0.f, a3 = 0.f, den = 0.f;

    auto edge4 = [&](const uint2 xu, bool masked, int jbase) {
        const float x0 = lo16(xu.x), x1 = hi16(xu.x);
        const float x2 = lo16(xu.y), x3 = hi16(xu.y);
        float t0 = x0 + xr0; t0 = fmaxf(t0, t0 * NEG_SLOPE);
        float t1 = x1 + xr1; t1 = fmaxf(t1, t1 * NEG_SLOPE);
        float t2 = x2 + xr2; t2 = fmaxf(t2, t2 * NEG_SLOPE);
        float t3 = x3 + xr3; t3 = fmaxf(t3, t3 * NEG_SLOPE);
        float p = fmaf(t0, at0, fmaf(t1, at1, fmaf(t2, at2, t3 * at3)));
        p = row16_sum(p);
        float w;
        if (masked) {
            w = __expf(fminf(p, 60.f));
            w = ((jbase + grp) < e1) ? w : 0.f;
        } else {
            w = __expf(p);
        }
        a0 = fmaf(w, x0, a0); a1 = fmaf(w, x1, a1);
        a2 = fmaf(w, x2, a2); a3 = fmaf(w, x3, a3);
        den += w;
    };

    uint s0_, s1_, s2_, s3_;
    {
        const int j0 = e0 + grp, j1 = j0 + 4, j2 = j0 + 8, j3 = j0 + 12;
        s0_ = (uint)col[j0 < e1 ? j0 : e1 - 1];
        s1_ = (uint)col[j1 < e1 ? j1 : e1 - 1];
        s2_ = (uint)col[j2 < e1 ? j2 : e1 - 1];
        s3_ = (uint)col[j3 < e1 ? j3 : e1 - 1];
    }
    for (int i = e0; i < iend; i += 16) {
        const uint2 xu0 = xl2v[(s0_ << 4) + m];
        const uint2 xu1 = xl2v[(s1_ << 4) + m];
        const uint2 xu2 = xl2v[(s2_ << 4) + m];
        const uint2 xu3 = xl2v[(s3_ << 4) + m];
        const int j0 = i + 16 + grp, j1 = j0 + 4, j2 = j0 + 8, j3 = j0 + 12;
        s0_ = (uint)col[j0 < e1 ? j0 : e1 - 1];
        s1_ = (uint)col[j1 < e1 ? j1 : e1 - 1];
        s2_ = (uint)col[j2 < e1 ? j2 : e1 - 1];
        s3_ = (uint)col[j3 < e1 ? j3 : e1 - 1];
        edge4(xu0, false, 0);
        edge4(xu1, false, 0);
        edge4(xu2, false, 0);
        edge4(xu3, false, 0);
    }
    const int rem = e1 - iend;
    if (rem > 0) {
        const uint2 xu0 = xl2v[(s0_ << 4) + m];
        const uint2 xu1 = xl2v[(s1_ << 4) + m];
        const uint2 xu2 = xl2v[(s2_ << 4) + m];
        const uint2 xu3 = xl2v[(s3_ << 4) + m];
        edge4(xu0, true, iend);
        if (rem > 4)  edge4(xu1, true, iend + 4);
        if (rem > 8)  edge4(xu2, true, iend + 8);
        if (rem > 12) edge4(xu3, true, iend + 12);
    }
    a0 += __shfl_xor(a0, 16); a0 += __shfl_xor(a0, 32);
    a1 += __shfl_xor(a1, 16); a1 += __shfl_xor(a1, 32);
    a2 += __shfl_xor(a2, 16); a2 += __shfl_xor(a2, 32);
    a3 += __shfl_xor(a3, 16); a3 += __shfl_xor(a3, 32);
    den += __shfl_xor(den, 16); den += __shfl_xor(den, 32);
    if (lane < 16) {
        const float inv = 1.f / den;
        const uint2 biu = ((const uint2*)bias2)[m];
        const uint2 gu  = ((const uint2*)g2)[m];
        const uint2 bu  = ((const uint2*)bb2)[m];
        const uint2 mu  = ((const uint2*)m2)[m];
        const uint2 vu  = ((const uint2*)v2)[m];
        const uint2 sku = ((const uint2*)xskip)[(size_t)n * 16 + m];
        const uint2 wou = ((const uint2*)Wo)[m];
        float o0 = fmaf(a0, inv, lo16(biu.x));
        float o1 = fmaf(a1, inv, hi16(biu.x));
        float o2 = fmaf(a2, inv, lo16(biu.y));
        float o3 = fmaf(a3, inv, hi16(biu.y));
        float s0 = lo16(gu.x) * rsqrtf(lo16(vu.x) + BN_EPS);
        float s1 = hi16(gu.x) * rsqrtf(hi16(vu.x) + BN_EPS);
        float s2 = lo16(gu.y) * rsqrtf(lo16(vu.y) + BN_EPS);
        float s3 = hi16(gu.y) * rsqrtf(hi16(vu.y) + BN_EPS);
        float h0 = fmaxf((o0 - lo16(mu.x)) * s0 + lo16(bu.x), 0.f) + lo16(sku.x);
        float h1v = fmaxf((o1 - hi16(mu.x)) * s1 + hi16(bu.x), 0.f) + hi16(sku.x);
        float h2 = fmaxf((o2 - lo16(mu.y)) * s2 + lo16(bu.y), 0.f) + lo16(sku.y);
        float h3 = fmaxf((o3 - hi16(mu.y)) * s3 + hi16(bu.y), 0.f) + hi16(sku.y);
        float d = fmaf(h0, lo16(wou.x), fmaf(h1v, hi16(wou.x),
                  fmaf(h2, lo16(wou.y), h3 * hi16(wou.y))));
        d = row16_sum(d);
        if (m == 0) {
            float r = d + b2f(bo[0]);
            if (f32out) ((float*)out)[n] = r;
            else        ((ushort*)out)[n] = f2b(r);
        }
    }
}

extern "C" void kernel_launch(void* const* d_in, const int* in_sizes, int n_in,
                              void* d_out, int out_size, void* d_ws, size_t ws_size,
                              hipStream_t stream) {
    char* ws = (char*)d_ws;
    size_t off = 0;
    auto alloc = [&](size_t bytes) -> void* {
        void* p = ws + off;
        off += (bytes + 255) & ~(size_t)255;
        return p;
    };
    ushort* params  = (ushort*)alloc((size_t)127617 * 2);
    int*    exc     = (int*)alloc((size_t)(N_NODES + 1) * 4);
    int*    deg     = (int*)alloc((size_t)N_NODES * 4);
    int*    epos    = (int*)alloc((size_t)EP_EDGES * 4);
    int*    colbuf  = (int*)alloc((size_t)EP_EDGES * 4);
    int*    bsum    = (int*)alloc(64 * 4);
    int*    cparr   = (int*)alloc(64 * 4);
    ushort* xl1     = (ushort*)alloc((size_t)N_NODES * C1 * 2);
    ushort* xr1     = (ushort*)alloc((size_t)N_NODES * C1 * 2);
    ushort* xskip   = (ushort*)alloc((size_t)N_NODES * HID * 2);
    ushort* h1      = (ushort*)alloc((size_t)N_NODES * C1 * 2);
    ushort* xl2     = (ushort*)alloc((size_t)N_NODES * HID * 2);
    ushort* xr2     = (ushort*)alloc((size_t)N_NODES * HID * 2);
    ushort* swzWl1  = (ushort*)alloc((size_t)IN_DIM * C1 * 2);
    ushort* swzWr1  = (ushort*)alloc((size_t)IN_DIM * C1 * 2);
    ushort* swzWs   = (ushort*)alloc((size_t)IN_DIM * HID * 2);
    ushort* swzWl2  = (ushort*)alloc((size_t)C1 * HID * 2);
    ushort* swzWr2  = (ushort*)alloc((size_t)C1 * HID * 2);

    ushort* bl1c   = params + 40960;
    ushort* br1c   = params + 82176;
    ushort* att1c  = params + 82432;
    ushort* bias1c = params + 82688;
    ushort* g1c    = params + 82944;
    ushort* b1c    = params + 83200;
    ushort* m1c    = params + 83456;
    ushort* v1c    = params + 83712;
    ushort* bl2c   = params + 100352;
    ushort* br2c   = params + 116800;
    ushort* att2c  = params + 116864;
    ushort* bias2c = params + 116928;
    ushort* g2c    = params + 116992;
    ushort* b2c    = params + 117056;
    ushort* m2c    = params + 117120;
    ushort* v2c    = params + 117184;
    ushort* bsc    = params + 127488;
    ushort* Woc    = params + 127552;
    ushort* boc    = params + 127616;

    const int* ei_raw = (const int*)d_in[1];

    // ---- deg = 0 (needed by fused hist) ----
    hipMemsetAsync(deg, 0, (size_t)N_NODES * 4, stream);

    // ---- fused front-end: swizzle+params | hist(+epos) ----
    SW2 sw;
    sw.W[0] = d_in[2];  sw.D[0] = swzWl1; sw.NT[0] = 16; sw.base[0] = 0;      // Wl1
    sw.W[1] = d_in[4];  sw.D[1] = swzWr1; sw.NT[1] = 16; sw.base[1] = 5120;   // Wr1
    sw.W[2] = d_in[22]; sw.D[2] = swzWs;  sw.NT[2] = 4;  sw.base[2] = 10240;  // Ws
    sw.W[3] = d_in[12]; sw.D[3] = swzWl2; sw.NT[3] = 4;  sw.base[3] = 11520;  // Wl2
    sw.W[4] = d_in[14]; sw.D[4] = swzWr2; sw.NT[4] = 4;  sw.base[4] = 13568;  // Wr2
    const int spidx[19] = {3,5,6,7,8,9,10,11, 13,15,16,17,18,19,20,21, 23,24, 25};
    for (int i = 0; i < 19; ++i) sw.sp[i] = d_in[spidx[i]];
    sw.xraw = d_in[0];
    front_k<<<NB_SWZ + NB_HIST, 256, 0, stream>>>(ei_raw, deg, epos, sw, params);

    const int NB_S = (N_NODES + 1023) / 1024;      // 49

    // ---- CSR scan (2 launches) ----
    scan1_k<<<NB_S, 1024, 0, stream>>>(deg, exc, bsum);
    scan2_k<<<1, 64, 0, stream>>>(bsum, cparr, exc);

    // ---- fused: gemm3 | scatter ----
    scatgemm_k<<<NB_G3 + NB_HIST, 256, 0, stream>>>(
        d_in[0], swzWl1, swzWr1, swzWs, bl1c, br1c, bsc, xl1, xr1, xskip, N_NODES,
        ei_raw, epos, exc, cparr, colbuf);

    // ---- conv1 edge aggregation + BN1 + relu ----
    conv1_k<<<N_NODES, 256, 0, stream>>>(xl1, xr1, exc, cparr, colbuf, att1c, bias1c,
                                         g1c, b1c, m1c, v1c, h1);

    // ---- layer-2 linear transforms, fused MFMA ----
    gemm2_k<<<(N_NODES + 63) / 64, 256, 0, stream>>>(h1, swzWl2, swzWr2, bl2c, br2c,
                                                     xl2, xr2, N_NODES);

    // ---- conv2 + BN2 + relu + skip + output linear ----
    conv2_k<<<(N_NODES + 3) / 4, 256, 0, stream>>>(xl2, xr2, xskip, exc, cparr, colbuf,
                                                   att2c, bias2c, g2c, b2c, m2c, v2c,
                                                   Woc, boc, d_out, (const ushort*)d_in[0]);
}